// Round 1
// baseline (3920.111 us; speedup 1.0000x reference)
//
#include <hip/hip_runtime.h>

// FasterGRUTree on MI355X — round 0: correct fp32 fused baseline.
// One block = T=16 trees, 256 threads. Per child step: leaf GRU (h0=0) for the
// 16 (tree, leaf c) rows, then child-fold GRU step; finally node GRU (x=0).
// Weights stream from L2 (total ~1.6 MB, fully L2-resident).

namespace {

constexpr int NB    = 20000;  // trees
constexpr int C     = 8;      // children
constexpr int WORD  = 300;
constexpr int TAG   = 50;
constexpr int MEM   = 150;
constexpr int G3    = 450;    // 3*MEM
constexpr int KLEAF = 350;    // WORD+TAG
constexpr int KLP   = 352;    // padded so rows are 16B-aligned for float4
constexpr int KCH   = 250;    // MEM+2*TAG
constexpr int KCHP  = 252;
constexpr int HP    = 152;    // padded MEM
constexpr int T     = 16;     // trees per block (20000 = 16*1250 exactly)
constexpr int NT    = 256;    // threads per block

__device__ __forceinline__ float sigmoid_f(float x) {
  return 1.0f / (1.0f + __expf(-x));
}

__device__ __forceinline__ float tanh_f(float x) {
  x = fminf(fmaxf(x, -15.0f), 15.0f);   // avoid inf/inf
  float e = __expf(2.0f * x);
  return (e - 1.0f) / (e + 1.0f);
}

// Accumulate acc{1,2}[r] = b{1,2} + sum_k w{1,2}[k] * xt[r][k] over all T rows.
// Weight rows are 8B-aligned (row strides 350/250/150 floats are even), LDS
// rows are 16B-aligned (KPAD multiples of 4). All-lane LDS reads of the same
// address broadcast (no bank conflict).
template<int KACT, int KPAD>
__device__ __forceinline__ void mat_pass(const float (*xt)[KPAD],
                                         const float* __restrict__ w1,
                                         const float* __restrict__ w2,
                                         float b1, float b2,
                                         float acc1[T], float acc2[T]) {
#pragma unroll
  for (int r = 0; r < T; ++r) { acc1[r] = b1; acc2[r] = b2; }
  constexpr int K4 = (KACT / 4) * 4;
  for (int k = 0; k < K4; k += 4) {
    float2 a1 = *(const float2*)(w1 + k);
    float2 c1 = *(const float2*)(w1 + k + 2);
    float2 a2 = *(const float2*)(w2 + k);
    float2 c2 = *(const float2*)(w2 + k + 2);
#pragma unroll
    for (int r = 0; r < T; ++r) {
      float4 xv = *(const float4*)(&xt[r][k]);
      acc1[r] = fmaf(a1.x, xv.x, fmaf(a1.y, xv.y,
                fmaf(c1.x, xv.z, fmaf(c1.y, xv.w, acc1[r]))));
      acc2[r] = fmaf(a2.x, xv.x, fmaf(a2.y, xv.y,
                fmaf(c2.x, xv.z, fmaf(c2.y, xv.w, acc2[r]))));
    }
  }
  if (KACT > K4) {  // 2 leftover columns (350/250/150 are all K4+2)
    float2 a1 = *(const float2*)(w1 + K4);
    float2 a2 = *(const float2*)(w2 + K4);
#pragma unroll
    for (int r = 0; r < T; ++r) {
      float2 xv = *(const float2*)(&xt[r][K4]);
      acc1[r] = fmaf(a1.x, xv.x, fmaf(a1.y, xv.y, acc1[r]));
      acc2[r] = fmaf(a2.x, xv.x, fmaf(a2.y, xv.y, acc2[r]));
    }
  }
}

__global__ __launch_bounds__(NT, 1)
void gru_tree_kernel(const float* __restrict__ embs,        // [B,C,WORD]
                     const float* __restrict__ tags,        // [B,C,TAG]
                     const float* __restrict__ tag_parent,  // [B,TAG]
                     const float* __restrict__ w_ih_leaf,   // [450,350]
                     const float* __restrict__ b_ih_leaf,   // [450]
                     const float* __restrict__ b_hh_leaf,   // [450]
                     const float* __restrict__ w_ih_child,  // [450,250]
                     const float* __restrict__ w_hh_child,  // [450,150]
                     const float* __restrict__ b_ih_child,  // [450]
                     const float* __restrict__ b_hh_child,  // [450]
                     const float* __restrict__ w_hh_node,   // [450,150]
                     const float* __restrict__ b_ih_node,   // [450]
                     const float* __restrict__ b_hh_node,   // [450]
                     float* __restrict__ out) {             // [B,MEM]
  __shared__ float xle[T][KLP];   // leaf inputs (emb|tag)           22528 B
  __shared__ float srz[T][300];   // r,z pre-activations (ih+hh)     19200 B
  __shared__ float sni[T][MEM];   // n pre-activation, ih part        9600 B
  __shared__ float snh[T][MEM];   // n pre-activation, hh part        9600 B
  __shared__ float xch[T][KCHP];  // child input (h_leaf|tag|tag_p)  16128 B
  __shared__ float hst[T][HP];    // running fold state               9728 B

  const int tid = threadIdx.x;
  const int b0  = blockIdx.x * T;

  for (int i = tid; i < T * HP; i += NT) (&hst[0][0])[i] = 0.0f;
  __syncthreads();

  const int  g1   = tid;               // gate row 1 (always < 300)
  const int  g2r  = tid + NT;          // gate row 2 (real)
  const bool has2 = (g2r < G3);
  const int  g2   = has2 ? g2r : (G3 - 1);  // clamped (dup work, not stored)

  float acc1[T], acc2[T], hac1[T], hac2[T];

  for (int c = 0; c < C; ++c) {
    // ---- stage leaf inputs x = [emb, tag] for the 16 (tree, c) rows
    for (int i = tid; i < T * KLEAF; i += NT) {
      int r = i / KLEAF, k = i - r * KLEAF;
      size_t b = (size_t)(b0 + r);
      xle[r][k] = (k < WORD) ? embs[(b * C + c) * WORD + k]
                             : tags[(b * C + c) * TAG + (k - WORD)];
    }
    __syncthreads();

    // ---- leaf GRU pre-activations: gi = x@Wih^T + b_ih; gh = b_hh (h0=0)
    mat_pass<KLEAF, KLP>(xle,
                         w_ih_leaf + (size_t)g1 * KLEAF,
                         w_ih_leaf + (size_t)g2 * KLEAF,
                         b_ih_leaf[g1], b_ih_leaf[g2], acc1, acc2);
    {
      float bh1 = b_hh_leaf[g1];
      float bh2 = b_hh_leaf[g2];
#pragma unroll
      for (int r = 0; r < T; ++r) {
        srz[r][g1] = acc1[r] + bh1;                       // g1 < 300 always
        if (has2) {
          if (g2 < 300) srz[r][g2] = acc2[r] + bh2;
          else          sni[r][g2 - 300] = acc2[r];       // b_hh_n read later
        }
      }
    }
    __syncthreads();

    // ---- leaf gate math -> h_leaf into xch[:,0:150]
    for (int i = tid; i < T * MEM; i += NT) {
      int r = i / MEM, j = i - r * MEM;
      float rg = sigmoid_f(srz[r][j]);
      float zg = sigmoid_f(srz[r][MEM + j]);
      float ng = tanh_f(sni[r][j] + rg * b_hh_leaf[2 * MEM + j]);
      xch[r][j] = (1.0f - zg) * ng;                       // + zg*0
    }
    // ---- xch tag parts
    for (int i = tid; i < T * 2 * TAG; i += NT) {
      int r = i / (2 * TAG), k = i - r * (2 * TAG);
      size_t b = (size_t)(b0 + r);
      xch[r][MEM + k] = (k < TAG) ? tags[(b * C + c) * TAG + k]
                                  : tag_parent[b * TAG + (k - TAG)];
    }
    __syncthreads();

    // ---- child GRU step: gi over xch (K=250), gh over hst (K=150)
    mat_pass<KCH, KCHP>(xch,
                        w_ih_child + (size_t)g1 * KCH,
                        w_ih_child + (size_t)g2 * KCH,
                        b_ih_child[g1], b_ih_child[g2], acc1, acc2);
    mat_pass<MEM, HP>(hst,
                      w_hh_child + (size_t)g1 * MEM,
                      w_hh_child + (size_t)g2 * MEM,
                      b_hh_child[g1], b_hh_child[g2], hac1, hac2);
#pragma unroll
    for (int r = 0; r < T; ++r) {
      srz[r][g1] = acc1[r] + hac1[r];                     // g1 < 300 always
      if (has2) {
        if (g2 < 300) srz[r][g2] = acc2[r] + hac2[r];
        else { sni[r][g2 - 300] = acc2[r]; snh[r][g2 - 300] = hac2[r]; }
      }
    }
    __syncthreads();

    // ---- child gate math -> update hst
    for (int i = tid; i < T * MEM; i += NT) {
      int r = i / MEM, j = i - r * MEM;
      float rg = sigmoid_f(srz[r][j]);
      float zg = sigmoid_f(srz[r][MEM + j]);
      float ng = tanh_f(sni[r][j] + rg * snh[r][j]);
      hst[r][j] = (1.0f - zg) * ng + zg * hst[r][j];
    }
    __syncthreads();
  }

  // ---- node GRU: gi = b_ih_node (x=0), gh = hst@Whh_node^T + b_hh_node
  mat_pass<MEM, HP>(hst,
                    w_hh_node + (size_t)g1 * MEM,
                    w_hh_node + (size_t)g2 * MEM,
                    b_hh_node[g1], b_hh_node[g2], hac1, hac2);
  {
    float bi1 = b_ih_node[g1];
    float bi2 = b_ih_node[g2];
#pragma unroll
    for (int r = 0; r < T; ++r) {
      srz[r][g1] = bi1 + hac1[r];                         // g1 < 300 always
      if (has2) {
        if (g2 < 300) srz[r][g2] = bi2 + hac2[r];
        else { sni[r][g2 - 300] = bi2; snh[r][g2 - 300] = hac2[r]; }
      }
    }
  }
  __syncthreads();
  for (int i = tid; i < T * MEM; i += NT) {
    int r = i / MEM, j = i - r * MEM;
    float rg = sigmoid_f(srz[r][j]);
    float zg = sigmoid_f(srz[r][MEM + j]);
    float ng = tanh_f(sni[r][j] + rg * snh[r][j]);
    out[(size_t)(b0 + r) * MEM + j] = (1.0f - zg) * ng + zg * hst[r][j];
  }
}

}  // namespace

extern "C" void kernel_launch(void* const* d_in, const int* in_sizes, int n_in,
                              void* d_out, int out_size, void* d_ws, size_t ws_size,
                              hipStream_t stream) {
  const float* embs       = (const float*)d_in[0];
  const float* tags       = (const float*)d_in[1];
  const float* tag_parent = (const float*)d_in[2];
  const float* w_ih_leaf  = (const float*)d_in[3];
  // d_in[4] w_hh_leaf unused: h0 = 0 so gh_leaf = b_hh_leaf
  const float* b_ih_leaf  = (const float*)d_in[5];
  const float* b_hh_leaf  = (const float*)d_in[6];
  const float* w_ih_child = (const float*)d_in[7];
  const float* w_hh_child = (const float*)d_in[8];
  const float* b_ih_child = (const float*)d_in[9];
  const float* b_hh_child = (const float*)d_in[10];
  // d_in[11] w_ih_node unused: x = 0 so gi_node = b_ih_node
  const float* w_hh_node  = (const float*)d_in[12];
  const float* b_ih_node  = (const float*)d_in[13];
  const float* b_hh_node  = (const float*)d_in[14];
  float* out = (float*)d_out;

  dim3 grid(NB / T);  // 1250 blocks, exact
  gru_tree_kernel<<<grid, NT, 0, stream>>>(
      embs, tags, tag_parent,
      w_ih_leaf, b_ih_leaf, b_hh_leaf,
      w_ih_child, w_hh_child, b_ih_child, b_hh_child,
      w_hh_node, b_ih_node, b_hh_node, out);
}

// Round 2
// 511.257 us; speedup vs baseline: 7.6676x; 7.6676x over previous
//
#include <hip/hip_runtime.h>

// FasterGRUTree R1: fp16 MFMA (16x16x32) fused kernel.
// prep kernel: fp32 weights -> fp16 fragment-ordered B operands + permuted bias tables in d_ws.
// main kernel: 250 blocks x 80 trees, 640 threads = 10 waves; wave w owns j-tile w (16 cols of
// the 150-dim output, padded to 160) for all five 16-tree m-tiles.

typedef _Float16 f16;
typedef _Float16 f16x8 __attribute__((ext_vector_type(8)));
typedef float f32x4 __attribute__((ext_vector_type(4)));

namespace {

constexpr int NB   = 20000;
constexpr int CCH  = 8;
constexpr int WORD = 300;
constexpr int TAGD = 50;
constexpr int MEMD = 150;

constexpr int BM    = 80;    // trees per block (250 blocks exact)
constexpr int NT    = 640;   // 10 waves
constexpr int XLE_S = 360;   // xle row stride (f16): K=352 tiles + pad, 720B rows (~2-way banks)
constexpr int XCH_S = 440;   // xch row stride (f16): K=416 + pad, 880B rows (~2-way banks)

constexpr int KT_L = 11;     // leaf K tiles   (352 = WORD+TAG padded)
constexpr int KT_C = 13;     // concat K tiles (416 = 256 x_child + 160 h)
constexpr int KT_N = 5;      // node K tiles   (160 = h)
constexpr int NTILE = 30;    // n-tiles: 3 gates x 10 j-tiles

// ws layout (bytes)
constexpr size_t OFF_WL   = 0;
constexpr size_t OFF_WC   = OFF_WL + (size_t)KT_L * NTILE * 64 * 16;   // 337920
constexpr size_t OFF_WN   = OFF_WC + (size_t)KT_C * NTILE * 64 * 16;   // 737280
constexpr size_t OFF_BIAS = OFF_WN + (size_t)KT_N * NTILE * 64 * 16;   // 890880
// bias arrays, 12 x 160 fp32:
// 0 bL_r(sum) 1 bL_z(sum) 2 bL_in 3 bL_hn | 4 bC_r 5 bC_z 6 bC_in 7 bC_hn | 8 bN_r 9 bN_z 10 bN_in 11 bN_hn

__device__ __forceinline__ float sigmoid_f(float x) {
  return 1.0f / (1.0f + __expf(-x));
}
__device__ __forceinline__ float tanh_f(float x) {
  float ax = fabsf(x);
  float e  = __expf(-2.0f * ax);
  float t  = (1.0f - e) / (1.0f + e);
  return copysignf(t, x);
}

// ---------------- prep: build fp16 fragment-ordered weights + bias tables ----------------
__global__ void prep_kernel(const float* __restrict__ w_ih_leaf,
                            const float* __restrict__ b_ih_leaf,
                            const float* __restrict__ b_hh_leaf,
                            const float* __restrict__ w_ih_child,
                            const float* __restrict__ w_hh_child,
                            const float* __restrict__ b_ih_child,
                            const float* __restrict__ b_hh_child,
                            const float* __restrict__ w_hh_node,
                            const float* __restrict__ b_ih_node,
                            const float* __restrict__ b_hh_node,
                            char* __restrict__ ws) {
  const int NWL = KT_L * NTILE * 64;   // 21120
  const int NWC = KT_C * NTILE * 64;   // 24960
  const int NWN = KT_N * NTILE * 64;   //  9600
  int t = blockIdx.x * blockDim.x + threadIdx.x;

  if (t < NWL) {  // leaf: B[k][g] = w_ih_leaf[g][k], K=352, gate-permuted cols
    int kt = t / (NTILE * 64), rem = t % (NTILE * 64);
    int nt = rem / 64, l = rem % 64;
    int gate = nt / 10, jt = nt % 10;
    int j = jt * 16 + (l & 15);
    bool valid = j < MEMD;
    int g = gate * MEMD + (valid ? j : 0);
    f16x8 v;
#pragma unroll
    for (int e = 0; e < 8; ++e) {
      int k = kt * 32 + ((l >> 4) * 8) + e;
      float x = (valid && k < WORD + TAGD) ? w_ih_leaf[g * (WORD + TAGD) + k] : 0.0f;
      v[e] = (f16)x;
    }
    ((f16x8*)(ws + OFF_WL))[t] = v;
    return;
  }
  t -= NWL;
  if (t < NWC) {  // concat: k<250 w_ih_child | 250..255 zero | 256..405 w_hh_child | pad
    int kt = t / (NTILE * 64), rem = t % (NTILE * 64);
    int nt = rem / 64, l = rem % 64;
    int gate = nt / 10, jt = nt % 10;
    int j = jt * 16 + (l & 15);
    bool valid = j < MEMD;
    int g = gate * MEMD + (valid ? j : 0);
    f16x8 v;
#pragma unroll
    for (int e = 0; e < 8; ++e) {
      int k = kt * 32 + ((l >> 4) * 8) + e;
      float x = 0.0f;
      if (valid) {
        if (k < 250)                    x = w_ih_child[g * 250 + k];
        else if (k >= 256 && k < 406)   x = w_hh_child[g * MEMD + (k - 256)];
      }
      v[e] = (f16)x;
    }
    ((f16x8*)(ws + OFF_WC))[t] = v;
    return;
  }
  t -= NWC;
  if (t < NWN) {  // node: K=160 over h
    int kt = t / (NTILE * 64), rem = t % (NTILE * 64);
    int nt = rem / 64, l = rem % 64;
    int gate = nt / 10, jt = nt % 10;
    int j = jt * 16 + (l & 15);
    bool valid = j < MEMD;
    int g = gate * MEMD + (valid ? j : 0);
    f16x8 v;
#pragma unroll
    for (int e = 0; e < 8; ++e) {
      int k = kt * 32 + ((l >> 4) * 8) + e;
      float x = (valid && k < MEMD) ? w_hh_node[g * MEMD + k] : 0.0f;
      v[e] = (f16)x;
    }
    ((f16x8*)(ws + OFF_WN))[t] = v;
    return;
  }
  t -= NWN;
  if (t < 12 * 160) {  // bias tables
    int arr = t / 160, j = t % 160;
    float v = 0.0f;
    if (j < MEMD) {
      switch (arr) {
        case 0:  v = b_ih_leaf[j] + b_hh_leaf[j]; break;
        case 1:  v = b_ih_leaf[MEMD + j] + b_hh_leaf[MEMD + j]; break;
        case 2:  v = b_ih_leaf[2 * MEMD + j]; break;
        case 3:  v = b_hh_leaf[2 * MEMD + j]; break;
        case 4:  v = b_ih_child[j] + b_hh_child[j]; break;
        case 5:  v = b_ih_child[MEMD + j] + b_hh_child[MEMD + j]; break;
        case 6:  v = b_ih_child[2 * MEMD + j]; break;
        case 7:  v = b_hh_child[2 * MEMD + j]; break;
        case 8:  v = b_ih_node[j] + b_hh_node[j]; break;
        case 9:  v = b_ih_node[MEMD + j] + b_hh_node[MEMD + j]; break;
        case 10: v = b_ih_node[2 * MEMD + j]; break;
        case 11: v = b_hh_node[2 * MEMD + j]; break;
      }
    }
    ((float*)(ws + OFF_BIAS))[arr * 160 + j] = v;
  }
}

// ---------------- main fused kernel ----------------
__global__ __launch_bounds__(NT, 1)
void gru_tree_mfma(const float* __restrict__ embs,
                   const float* __restrict__ tags,
                   const float* __restrict__ tag_parent,
                   const char*  __restrict__ ws,
                   float* __restrict__ out) {
  extern __shared__ char smem[];
  f16* xle = (f16*)smem;                 // [BM][XLE_S]  57600 B
  f16* xch = xle + BM * XLE_S;           // [BM][XCH_S]  70400 B  (0..255 x_child | 256..415 h)

  const f16x8* WL = (const f16x8*)(ws + OFF_WL);
  const f16x8* WC = (const f16x8*)(ws + OFF_WC);
  const f16x8* WN = (const f16x8*)(ws + OFF_WN);
  const float* BIAS = (const float*)(ws + OFF_BIAS);

  const int tid  = threadIdx.x;
  const int lane = tid & 63;
  const int w    = tid >> 6;             // wave id = j-tile, 0..9
  const int b0   = blockIdx.x * BM;

  const int arow  = lane & 15;           // A-frag row within m-tile
  const int acol8 = (lane >> 4) * 8;     // A-frag k offset within k-tile
  const int qrow  = (lane >> 4) * 4;     // D row base
  const int j     = w * 16 + (lane & 15);
  const bool jok  = (j < MEMD);

  const float bLr = BIAS[0 * 160 + j], bLz = BIAS[1 * 160 + j];
  const float bLi = BIAS[2 * 160 + j], bLh = BIAS[3 * 160 + j];
  const float bCr = BIAS[4 * 160 + j], bCz = BIAS[5 * 160 + j];
  const float bCi = BIAS[6 * 160 + j], bCh = BIAS[7 * 160 + j];
  const float bNr = BIAS[8 * 160 + j], bNz = BIAS[9 * 160 + j];
  const float bNi = BIAS[10 * 160 + j], bNh = BIAS[11 * 160 + j];

  // ---- one-time staging: zero xch[250..440), tag_parent -> cols 200..250
  for (int i = tid; i < BM * 190; i += NT) {
    int r = i / 190, cc = i % 190;
    xch[r * XCH_S + 250 + cc] = (f16)0.0f;
  }
  for (int i = tid; i < BM * TAGD; i += NT) {
    int r = i / TAGD, tix = i % TAGD;
    xch[r * XCH_S + 200 + tix] = (f16)tag_parent[(size_t)(b0 + r) * TAGD + tix];
  }

  f32x4 aR[5], aZ[5], aNi[5], aNh[5];

  for (int c = 0; c < CCH; ++c) {
    // ---- stage leaf input [emb|tag|0] and this child's tag (cols 150..200)
    for (int i = tid; i < BM * (XLE_S / 2); i += NT) {
      int r = i / (XLE_S / 2), k2 = i % (XLE_S / 2);
      int k = k2 * 2;
      size_t row = (size_t)(b0 + r) * CCH + c;
      float2 v;
      if (k < WORD)            v = *(const float2*)(embs + row * WORD + k);
      else if (k < WORD + TAGD) v = *(const float2*)(tags + row * TAGD + (k - WORD));
      else                     v = make_float2(0.0f, 0.0f);
      xle[r * XLE_S + k]     = (f16)v.x;
      xle[r * XLE_S + k + 1] = (f16)v.y;
    }
    for (int i = tid; i < BM * TAGD; i += NT) {
      int r = i / TAGD, tix = i % TAGD;
      xch[r * XCH_S + MEMD + tix] =
          (f16)tags[((size_t)(b0 + r) * CCH + c) * TAGD + tix];
    }
    __syncthreads();  // S1: staging + prev-step h writes visible

    // ---- leaf GEMM: preact[80,480] over K=352 (gh = bias only since h0=0)
#pragma unroll
    for (int m = 0; m < 5; ++m) { aR[m] = 0.f; aZ[m] = 0.f; aNi[m] = 0.f; }
    for (int kt = 0; kt < KT_L; ++kt) {
      f16x8 br = WL[(kt * NTILE + w) * 64 + lane];
      f16x8 bz = WL[(kt * NTILE + 10 + w) * 64 + lane];
      f16x8 bn = WL[(kt * NTILE + 20 + w) * 64 + lane];
      const f16* abase = xle + kt * 32 + acol8;
#pragma unroll
      for (int m = 0; m < 5; ++m) {
        f16x8 a = *(const f16x8*)(abase + (16 * m + arow) * XLE_S);
        aR[m]  = __builtin_amdgcn_mfma_f32_16x16x32_f16(a, br, aR[m], 0, 0, 0);
        aZ[m]  = __builtin_amdgcn_mfma_f32_16x16x32_f16(a, bz, aZ[m], 0, 0, 0);
        aNi[m] = __builtin_amdgcn_mfma_f32_16x16x32_f16(a, bn, aNi[m], 0, 0, 0);
      }
    }
    // ---- leaf gate math -> h_leaf into xch cols [0,150)
#pragma unroll
    for (int m = 0; m < 5; ++m) {
#pragma unroll
      for (int q = 0; q < 4; ++q) {
        float rg = sigmoid_f(aR[m][q] + bLr);
        float zg = sigmoid_f(aZ[m][q] + bLz);
        float ng = tanh_f(aNi[m][q] + bLi + rg * bLh);
        float h  = (1.0f - zg) * ng;
        if (jok) xch[(16 * m + qrow + q) * XCH_S + j] = (f16)h;
      }
    }
    __syncthreads();  // S2: h_leaf visible

    // ---- concat GEMM: [x_child(256) | h(160)] @ [W_ih_child | W_hh_child]^T
#pragma unroll
    for (int m = 0; m < 5; ++m) { aR[m] = 0.f; aZ[m] = 0.f; aNi[m] = 0.f; aNh[m] = 0.f; }
    for (int kt = 0; kt < KT_C; ++kt) {
      f16x8 br = WC[(kt * NTILE + w) * 64 + lane];
      f16x8 bz = WC[(kt * NTILE + 10 + w) * 64 + lane];
      f16x8 bn = WC[(kt * NTILE + 20 + w) * 64 + lane];
      const f16* abase = xch + kt * 32 + acol8;
#pragma unroll
      for (int m = 0; m < 5; ++m) {
        f16x8 a = *(const f16x8*)(abase + (16 * m + arow) * XCH_S);
        aR[m] = __builtin_amdgcn_mfma_f32_16x16x32_f16(a, br, aR[m], 0, 0, 0);
        aZ[m] = __builtin_amdgcn_mfma_f32_16x16x32_f16(a, bz, aZ[m], 0, 0, 0);
        if (kt < 8) aNi[m] = __builtin_amdgcn_mfma_f32_16x16x32_f16(a, bn, aNi[m], 0, 0, 0);
        else        aNh[m] = __builtin_amdgcn_mfma_f32_16x16x32_f16(a, bn, aNh[m], 0, 0, 0);
      }
    }
    __syncthreads();  // S3: all xch GEMM reads done before h update

    // ---- child gate math -> update h (xch cols 256+j)
#pragma unroll
    for (int m = 0; m < 5; ++m) {
#pragma unroll
      for (int q = 0; q < 4; ++q) {
        int row = 16 * m + qrow + q;
        float hp = (float)xch[row * XCH_S + 256 + j];
        float rg = sigmoid_f(aR[m][q] + bCr);
        float zg = sigmoid_f(aZ[m][q] + bCz);
        float ng = tanh_f(aNi[m][q] + bCi + rg * (aNh[m][q] + bCh));
        float h  = (1.0f - zg) * ng + zg * hp;
        if (jok) xch[row * XCH_S + 256 + j] = (f16)h;
      }
    }
  }

  __syncthreads();  // S4: final h visible for node GEMM

  // ---- node GRU: gi = b_ih_node (x=0); gh = h @ W_hh_node^T
#pragma unroll
  for (int m = 0; m < 5; ++m) { aR[m] = 0.f; aZ[m] = 0.f; aNh[m] = 0.f; }
  for (int kt = 0; kt < KT_N; ++kt) {
    f16x8 br = WN[(kt * NTILE + w) * 64 + lane];
    f16x8 bz = WN[(kt * NTILE + 10 + w) * 64 + lane];
    f16x8 bn = WN[(kt * NTILE + 20 + w) * 64 + lane];
    const f16* abase = xch + 256 + kt * 32 + acol8;
#pragma unroll
    for (int m = 0; m < 5; ++m) {
      f16x8 a = *(const f16x8*)(abase + (16 * m + arow) * XCH_S);
      aR[m]  = __builtin_amdgcn_mfma_f32_16x16x32_f16(a, br, aR[m], 0, 0, 0);
      aZ[m]  = __builtin_amdgcn_mfma_f32_16x16x32_f16(a, bz, aZ[m], 0, 0, 0);
      aNh[m] = __builtin_amdgcn_mfma_f32_16x16x32_f16(a, bn, aNh[m], 0, 0, 0);
    }
  }
#pragma unroll
  for (int m = 0; m < 5; ++m) {
#pragma unroll
    for (int q = 0; q < 4; ++q) {
      int row = 16 * m + qrow + q;
      float hp = (float)xch[row * XCH_S + 256 + j];
      float rg = sigmoid_f(aR[m][q] + bNr);
      float zg = sigmoid_f(aZ[m][q] + bNz);
      float ng = tanh_f(bNi + rg * (aNh[m][q] + bNh));
      float o  = (1.0f - zg) * ng + zg * hp;
      if (jok) out[(size_t)(b0 + row) * MEMD + j] = o;
    }
  }
}

}  // namespace

extern "C" void kernel_launch(void* const* d_in, const int* in_sizes, int n_in,
                              void* d_out, int out_size, void* d_ws, size_t ws_size,
                              hipStream_t stream) {
  const float* embs       = (const float*)d_in[0];
  const float* tags       = (const float*)d_in[1];
  const float* tag_parent = (const float*)d_in[2];
  const float* w_ih_leaf  = (const float*)d_in[3];
  // d_in[4] w_hh_leaf unused (h0 = 0)
  const float* b_ih_leaf  = (const float*)d_in[5];
  const float* b_hh_leaf  = (const float*)d_in[6];
  const float* w_ih_child = (const float*)d_in[7];
  const float* w_hh_child = (const float*)d_in[8];
  const float* b_ih_child = (const float*)d_in[9];
  const float* b_hh_child = (const float*)d_in[10];
  // d_in[11] w_ih_node unused (x = 0)
  const float* w_hh_node  = (const float*)d_in[12];
  const float* b_ih_node  = (const float*)d_in[13];
  const float* b_hh_node  = (const float*)d_in[14];
  float* out = (float*)d_out;
  char*  ws  = (char*)d_ws;

  // prep: 57600 threads exactly (21120 + 24960 + 9600 + 1920)
  prep_kernel<<<225, 256, 0, stream>>>(w_ih_leaf, b_ih_leaf, b_hh_leaf,
                                       w_ih_child, w_hh_child, b_ih_child, b_hh_child,
                                       w_hh_node, b_ih_node, b_hh_node, ws);

  constexpr int LDS_BYTES = (BM * XLE_S + BM * XCH_S) * 2;  // 128000
  hipFuncSetAttribute((const void*)gru_tree_mfma,
                      hipFuncAttributeMaxDynamicSharedMemorySize, LDS_BYTES);
  gru_tree_mfma<<<NB / BM, NT, LDS_BYTES, stream>>>(embs, tags, tag_parent, ws, out);
}

// Round 3
// 469.881 us; speedup vs baseline: 8.3428x; 1.0881x over previous
//
#include <hip/hip_runtime.h>

// FasterGRUTree R2: split parallel leaf phase from sequential fold phase.
//  prep2_kernel: fp32 weights -> f16 fragment-ordered B operands + bias tables (ws).
//  leaf_kernel:  250x8 blocks, 640 thr; leaf GRU for all (tree,child); h_leaf -> ws f16.
//  fold_kernel:  250 blocks, 640 thr; 8-step child fold + node GRU, x(c+1) prefetched.
// Fallback: if ws_size < ~49.5 MB, run the proven R1 monolithic kernel.

typedef _Float16 f16;
typedef _Float16 f16x8 __attribute__((ext_vector_type(8)));
typedef float f32x4 __attribute__((ext_vector_type(4)));

namespace {

constexpr int NTREE = 20000;
constexpr int CCH   = 8;
constexpr int WORD  = 300;
constexpr int TAGD  = 50;
constexpr int MEMD  = 150;

__device__ __forceinline__ float sigmoid_f(float x) {
  return 1.0f / (1.0f + __expf(-x));
}
__device__ __forceinline__ float tanh_f(float x) {
  float ax = fabsf(x);
  float e  = __expf(-2.0f * ax);
  float t  = (1.0f - e) / (1.0f + e);
  return copysignf(t, x);
}

// ================= new-path layout =================
constexpr int KT_L = 11;   // leaf K tiles (352 = WORD+TAG padded)
constexpr int KT_I = 8;    // x_child K tiles (256 = h|00|tag|tagp|0000)
constexpr int KT_H = 5;    // hh K tiles (160)
constexpr int KT_N = 5;    // node K tiles (160)
constexpr int NTILE = 30;  // 3 gates x 10 j-tiles

constexpr size_t OFF_WL   = 0;
constexpr size_t OFF_WI   = OFF_WL + (size_t)KT_L * NTILE * 64 * 16;  // 337920
constexpr size_t OFF_WH   = OFF_WI + (size_t)KT_I * NTILE * 64 * 16;  // 583680
constexpr size_t OFF_WN   = OFF_WH + (size_t)KT_H * NTILE * 64 * 16;  // 737280
constexpr size_t OFF_BIAS = OFF_WN + (size_t)KT_N * NTILE * 64 * 16;  // 890880
constexpr size_t OFF_H    = OFF_BIAS + 12 * 160 * 4;                  // 898560
constexpr int    HW_S     = 152;  // h_leaf row stride (cols 150,151 zeroed)
constexpr size_t WS_NEED  = OFF_H + (size_t)CCH * NTREE * HW_S * 2;   // 49,538,560

// bias arrays (12 x 160 f32):
// 0 bL_r 1 bL_z 2 bL_in 3 bL_hn | 4 bC_r 5 bC_z 6 bC_in 7 bC_hn | 8 bN_r 9 bN_z 10 bN_in 11 bN_hn
// (r/z arrays hold b_ih+b_hh sums)

__global__ void prep2_kernel(const float* __restrict__ w_ih_leaf,
                             const float* __restrict__ b_ih_leaf,
                             const float* __restrict__ b_hh_leaf,
                             const float* __restrict__ w_ih_child,
                             const float* __restrict__ w_hh_child,
                             const float* __restrict__ b_ih_child,
                             const float* __restrict__ b_hh_child,
                             const float* __restrict__ w_hh_node,
                             const float* __restrict__ b_ih_node,
                             const float* __restrict__ b_hh_node,
                             char* __restrict__ ws) {
  const int NWL = KT_L * NTILE * 64;  // 21120
  const int NWI = KT_I * NTILE * 64;  // 15360
  const int NWH = KT_H * NTILE * 64;  //  9600
  const int NWN = KT_N * NTILE * 64;  //  9600
  int t = blockIdx.x * blockDim.x + threadIdx.x;

  if (t < NWL) {  // w_ih_leaf, K=352
    int kt = t / (NTILE * 64), rem = t % (NTILE * 64);
    int nt = rem / 64, l = rem % 64;
    int gate = nt / 10, jt = nt % 10;
    int j = jt * 16 + (l & 15);
    bool valid = j < MEMD;
    int g = gate * MEMD + (valid ? j : 0);
    f16x8 v;
#pragma unroll
    for (int e = 0; e < 8; ++e) {
      int k = kt * 32 + ((l >> 4) * 8) + e;
      float x = (valid && k < WORD + TAGD) ? w_ih_leaf[g * (WORD + TAGD) + k] : 0.0f;
      v[e] = (f16)x;
    }
    ((f16x8*)(ws + OFF_WL))[t] = v;
    return;
  }
  t -= NWL;
  if (t < NWI) {  // w_ih_child remapped: k<150 state | 150,151 zero | 152..201 tag | 202..251 tagp | 252..255 zero
    int kt = t / (NTILE * 64), rem = t % (NTILE * 64);
    int nt = rem / 64, l = rem % 64;
    int gate = nt / 10, jt = nt % 10;
    int j = jt * 16 + (l & 15);
    bool valid = j < MEMD;
    int g = gate * MEMD + (valid ? j : 0);
    f16x8 v;
#pragma unroll
    for (int e = 0; e < 8; ++e) {
      int k = kt * 32 + ((l >> 4) * 8) + e;
      int src = (k < 150) ? k : (k >= 152 && k < 252) ? (k - 2) : -1;
      float x = (valid && src >= 0) ? w_ih_child[g * 250 + src] : 0.0f;
      v[e] = (f16)x;
    }
    ((f16x8*)(ws + OFF_WI))[t] = v;
    return;
  }
  t -= NWI;
  if (t < NWH) {  // w_hh_child, K=160
    int kt = t / (NTILE * 64), rem = t % (NTILE * 64);
    int nt = rem / 64, l = rem % 64;
    int gate = nt / 10, jt = nt % 10;
    int j = jt * 16 + (l & 15);
    bool valid = j < MEMD;
    int g = gate * MEMD + (valid ? j : 0);
    f16x8 v;
#pragma unroll
    for (int e = 0; e < 8; ++e) {
      int k = kt * 32 + ((l >> 4) * 8) + e;
      float x = (valid && k < MEMD) ? w_hh_child[g * MEMD + k] : 0.0f;
      v[e] = (f16)x;
    }
    ((f16x8*)(ws + OFF_WH))[t] = v;
    return;
  }
  t -= NWH;
  if (t < NWN) {  // w_hh_node, K=160
    int kt = t / (NTILE * 64), rem = t % (NTILE * 64);
    int nt = rem / 64, l = rem % 64;
    int gate = nt / 10, jt = nt % 10;
    int j = jt * 16 + (l & 15);
    bool valid = j < MEMD;
    int g = gate * MEMD + (valid ? j : 0);
    f16x8 v;
#pragma unroll
    for (int e = 0; e < 8; ++e) {
      int k = kt * 32 + ((l >> 4) * 8) + e;
      float x = (valid && k < MEMD) ? w_hh_node[g * MEMD + k] : 0.0f;
      v[e] = (f16)x;
    }
    ((f16x8*)(ws + OFF_WN))[t] = v;
    return;
  }
  t -= NWN;
  if (t < 12 * 160) {
    int arr = t / 160, j = t % 160;
    float v = 0.0f;
    if (j < MEMD) {
      switch (arr) {
        case 0:  v = b_ih_leaf[j] + b_hh_leaf[j]; break;
        case 1:  v = b_ih_leaf[MEMD + j] + b_hh_leaf[MEMD + j]; break;
        case 2:  v = b_ih_leaf[2 * MEMD + j]; break;
        case 3:  v = b_hh_leaf[2 * MEMD + j]; break;
        case 4:  v = b_ih_child[j] + b_hh_child[j]; break;
        case 5:  v = b_ih_child[MEMD + j] + b_hh_child[MEMD + j]; break;
        case 6:  v = b_ih_child[2 * MEMD + j]; break;
        case 7:  v = b_hh_child[2 * MEMD + j]; break;
        case 8:  v = b_ih_node[j] + b_hh_node[j]; break;
        case 9:  v = b_ih_node[MEMD + j] + b_hh_node[MEMD + j]; break;
        case 10: v = b_ih_node[2 * MEMD + j]; break;
        case 11: v = b_hh_node[2 * MEMD + j]; break;
      }
    }
    ((float*)(ws + OFF_BIAS))[arr * 160 + j] = v;
  }
}

// ---------------- leaf kernel: fully parallel over (tree, child) ----------------
__global__ __launch_bounds__(640)
void leaf_kernel(const float* __restrict__ embs,
                 const float* __restrict__ tags,
                 char* __restrict__ ws) {
  __shared__ f16 xle[80 * 360];   // 57600 B; stride 360 f16 = 720 B (good bank spread)
  const f16x8* WL   = (const f16x8*)(ws + OFF_WL);
  const float* BIAS = (const float*)(ws + OFF_BIAS);
  f16* hws = (f16*)(ws + OFF_H);

  const int tid = threadIdx.x, lane = tid & 63, w = tid >> 6;
  const int c = blockIdx.y, t0 = blockIdx.x * 80;
  const int arow = lane & 15, acol8 = (lane >> 4) * 8, qrow = (lane >> 4) * 4;
  const int j = w * 16 + (lane & 15);

  for (int i = tid; i < 80 * 150; i += 640) {
    int r = i / 150, k2 = i - r * 150;
    float2 v = *(const float2*)(embs + ((size_t)(t0 + r) * CCH + c) * WORD + 2 * k2);
    xle[r * 360 + 2 * k2]     = (f16)v.x;
    xle[r * 360 + 2 * k2 + 1] = (f16)v.y;
  }
  for (int i = tid; i < 80 * 25; i += 640) {
    int r = i / 25, k2 = i - r * 25;
    float2 v = *(const float2*)(tags + ((size_t)(t0 + r) * CCH + c) * TAGD + 2 * k2);
    xle[r * 360 + 300 + 2 * k2]     = (f16)v.x;
    xle[r * 360 + 300 + 2 * k2 + 1] = (f16)v.y;
  }
  for (int i = tid; i < 80; i += 640) {
    xle[i * 360 + 350] = (f16)0.0f;
    xle[i * 360 + 351] = (f16)0.0f;
  }
  __syncthreads();

  f32x4 aR[5], aZ[5], aN[5];
#pragma unroll
  for (int m = 0; m < 5; ++m) { aR[m] = 0.f; aZ[m] = 0.f; aN[m] = 0.f; }
  for (int kt = 0; kt < KT_L; ++kt) {
    f16x8 br = WL[(kt * NTILE + w) * 64 + lane];
    f16x8 bz = WL[(kt * NTILE + 10 + w) * 64 + lane];
    f16x8 bn = WL[(kt * NTILE + 20 + w) * 64 + lane];
    const f16* ab = xle + kt * 32 + acol8;
#pragma unroll
    for (int m = 0; m < 5; ++m) {
      f16x8 a = *(const f16x8*)(ab + (16 * m + arow) * 360);
      aR[m] = __builtin_amdgcn_mfma_f32_16x16x32_f16(a, br, aR[m], 0, 0, 0);
      aZ[m] = __builtin_amdgcn_mfma_f32_16x16x32_f16(a, bz, aZ[m], 0, 0, 0);
      aN[m] = __builtin_amdgcn_mfma_f32_16x16x32_f16(a, bn, aN[m], 0, 0, 0);
    }
  }

  const float bLr = BIAS[j], bLz = BIAS[160 + j], bLi = BIAS[320 + j], bLh = BIAS[480 + j];
#pragma unroll
  for (int m = 0; m < 5; ++m) {
#pragma unroll
    for (int q = 0; q < 4; ++q) {
      int row = 16 * m + qrow + q;
      float rg = sigmoid_f(aR[m][q] + bLr);
      float zg = sigmoid_f(aZ[m][q] + bLz);
      float ng = tanh_f(aN[m][q] + bLi + rg * bLh);
      float h  = (1.0f - zg) * ng;   // + zg*0
      if (j < HW_S)
        hws[((size_t)c * NTREE + t0 + row) * HW_S + j] = (f16)(j < MEMD ? h : 0.0f);
    }
  }
}

// ---------------- fold kernel: sequential 8-step child fold + node ----------------
__global__ __launch_bounds__(640)
void fold_kernel(const float* __restrict__ tags,
                 const float* __restrict__ tag_parent,
                 const char* __restrict__ ws,
                 float* __restrict__ out) {
  extern __shared__ char fsm[];
  f16* xch0 = (f16*)fsm;             // [80][264]  x_child buffers (double)
  f16* xch1 = xch0 + 80 * 264;
  f16* hls  = xch1 + 80 * 264;       // [80][168]  h state for A-frags

  const f16x8* WI   = (const f16x8*)(ws + OFF_WI);
  const f16x8* WH   = (const f16x8*)(ws + OFF_WH);
  const f16x8* WN   = (const f16x8*)(ws + OFF_WN);
  const float* BIAS = (const float*)(ws + OFF_BIAS);
  const f16*   hws  = (const f16*)(ws + OFF_H);

  const int tid = threadIdx.x, lane = tid & 63, w = tid >> 6;
  const int t0 = blockIdx.x * 80;
  const int arow = lane & 15, acol8 = (lane >> 4) * 8, qrow = (lane >> 4) * 4;
  const int j = w * 16 + (lane & 15);
  const bool jok = j < MEMD;

  const float bCr = BIAS[4 * 160 + j], bCz = BIAS[5 * 160 + j];
  const float bCi = BIAS[6 * 160 + j], bCh = BIAS[7 * 160 + j];
  const float bNr = BIAS[8 * 160 + j], bNz = BIAS[9 * 160 + j];
  const float bNi = BIAS[10 * 160 + j], bNh = BIAS[11 * 160 + j];

  // ---- prologue: zero h, stage tagp + zeros into both buffers, stage x(0)
  for (int i = tid; i < 1680; i += 640) ((int4*)hls)[i] = make_int4(0, 0, 0, 0);
  for (int i = tid; i < 80 * 25; i += 640) {
    int r = i / 25, k2 = i - r * 25;
    float2 v = *(const float2*)(tag_parent + (size_t)(t0 + r) * TAGD + 2 * k2);
    f16 a = (f16)v.x, b = (f16)v.y;
    xch0[r * 264 + 202 + 2 * k2] = a; xch0[r * 264 + 203 + 2 * k2] = b;
    xch1[r * 264 + 202 + 2 * k2] = a; xch1[r * 264 + 203 + 2 * k2] = b;
  }
  for (int i = tid; i < 80 * 4; i += 640) {
    int r = i >> 2, k = i & 3;
    xch0[r * 264 + 252 + k] = (f16)0.0f;
    xch1[r * 264 + 252 + k] = (f16)0.0f;
  }
#pragma unroll
  for (int s = 0; s < 3; ++s) {
    int i = tid + 640 * s;
    if (i < 1520) {
      int r = i / 19, q = i - r * 19;
      *(f16x8*)(xch0 + r * 264 + 8 * q) =
          *(const f16x8*)(hws + ((size_t)(t0 + r)) * HW_S + 8 * q);  // c=0
    }
  }
#pragma unroll
  for (int s = 0; s < 4; ++s) {
    int i = tid + 640 * s;
    if (i < 2000) {
      int r = i / 25, k2 = i - r * 25;
      float2 v = *(const float2*)(tags + ((size_t)(t0 + r) * CCH) * TAGD + 2 * k2);  // c=0
      xch0[r * 264 + 152 + 2 * k2] = (f16)v.x;
      xch0[r * 264 + 153 + 2 * k2] = (f16)v.y;
    }
  }
  __syncthreads();

  f32x4 hp[5];
#pragma unroll
  for (int m = 0; m < 5; ++m) hp[m] = 0.f;

  f16* xc = xch0;
  f16* xa = xch1;

  for (int c = 0; c < CCH; ++c) {
    // ---- issue prefetch of x(c+1) (T14: issue-early / write-late)
    f16x8 ph[3];
    float2 pt[4];
    if (c < 7) {
#pragma unroll
      for (int s = 0; s < 3; ++s) {
        int i = tid + 640 * s;
        if (i < 1520) {
          int r = i / 19, q = i - r * 19;
          ph[s] = *(const f16x8*)(hws + ((size_t)(c + 1) * NTREE + t0 + r) * HW_S + 8 * q);
        }
      }
#pragma unroll
      for (int s = 0; s < 4; ++s) {
        int i = tid + 640 * s;
        if (i < 2000) {
          int r = i / 25, k2 = i - r * 25;
          pt[s] = *(const float2*)(tags + ((size_t)(t0 + r) * CCH + (c + 1)) * TAGD + 2 * k2);
        }
      }
    }

    // ---- GEMMs: x-part (K=256) then h-part (K=160)
    f32x4 aR[5], aZ[5], aNi[5], aNh[5];
#pragma unroll
    for (int m = 0; m < 5; ++m) { aR[m] = 0.f; aZ[m] = 0.f; aNi[m] = 0.f; aNh[m] = 0.f; }
    for (int kt = 0; kt < KT_I; ++kt) {
      f16x8 br = WI[(kt * NTILE + w) * 64 + lane];
      f16x8 bz = WI[(kt * NTILE + 10 + w) * 64 + lane];
      f16x8 bn = WI[(kt * NTILE + 20 + w) * 64 + lane];
      const f16* ab = xc + kt * 32 + acol8;
#pragma unroll
      for (int m = 0; m < 5; ++m) {
        f16x8 a = *(const f16x8*)(ab + (16 * m + arow) * 264);
        aR[m]  = __builtin_amdgcn_mfma_f32_16x16x32_f16(a, br, aR[m], 0, 0, 0);
        aZ[m]  = __builtin_amdgcn_mfma_f32_16x16x32_f16(a, bz, aZ[m], 0, 0, 0);
        aNi[m] = __builtin_amdgcn_mfma_f32_16x16x32_f16(a, bn, aNi[m], 0, 0, 0);
      }
    }
    for (int kt = 0; kt < KT_H; ++kt) {
      f16x8 br = WH[(kt * NTILE + w) * 64 + lane];
      f16x8 bz = WH[(kt * NTILE + 10 + w) * 64 + lane];
      f16x8 bn = WH[(kt * NTILE + 20 + w) * 64 + lane];
      const f16* ab = hls + kt * 32 + acol8;
#pragma unroll
      for (int m = 0; m < 5; ++m) {
        f16x8 a = *(const f16x8*)(ab + (16 * m + arow) * 168);
        aR[m]  = __builtin_amdgcn_mfma_f32_16x16x32_f16(a, br, aR[m], 0, 0, 0);
        aZ[m]  = __builtin_amdgcn_mfma_f32_16x16x32_f16(a, bz, aZ[m], 0, 0, 0);
        aNh[m] = __builtin_amdgcn_mfma_f32_16x16x32_f16(a, bn, aNh[m], 0, 0, 0);
      }
    }
    __syncthreads();  // B1: all LDS reads of this step done

    // ---- write-late: staged x(c+1) into the other buffer
    if (c < 7) {
#pragma unroll
      for (int s = 0; s < 3; ++s) {
        int i = tid + 640 * s;
        if (i < 1520) {
          int r = i / 19, q = i - r * 19;
          *(f16x8*)(xa + r * 264 + 8 * q) = ph[s];
        }
      }
#pragma unroll
      for (int s = 0; s < 4; ++s) {
        int i = tid + 640 * s;
        if (i < 2000) {
          int r = i / 25, k2 = i - r * 25;
          xa[r * 264 + 152 + 2 * k2] = (f16)pt[s].x;
          xa[r * 264 + 153 + 2 * k2] = (f16)pt[s].y;
        }
      }
    }

    // ---- gate math; h kept in regs (hp) and mirrored to LDS for A-frags
#pragma unroll
    for (int m = 0; m < 5; ++m) {
#pragma unroll
      for (int q = 0; q < 4; ++q) {
        int row = 16 * m + qrow + q;
        float rg = sigmoid_f(aR[m][q] + bCr);
        float zg = sigmoid_f(aZ[m][q] + bCz);
        float ng = tanh_f(aNi[m][q] + bCi + rg * (aNh[m][q] + bCh));
        float h  = (1.0f - zg) * ng + zg * hp[m][q];
        hp[m][q] = h;
        if (jok) hls[row * 168 + j] = (f16)h;
      }
    }
    __syncthreads();  // B2: h + staged x visible
    f16* tsw = xc; xc = xa; xa = tsw;
  }

  // ---- node GRU: gi = b_ih_node (x=0); gh = h @ W_hh_node^T + b_hh_node
  f32x4 aR[5], aZ[5], aNh[5];
#pragma unroll
  for (int m = 0; m < 5; ++m) { aR[m] = 0.f; aZ[m] = 0.f; aNh[m] = 0.f; }
  for (int kt = 0; kt < KT_N; ++kt) {
    f16x8 br = WN[(kt * NTILE + w) * 64 + lane];
    f16x8 bz = WN[(kt * NTILE + 10 + w) * 64 + lane];
    f16x8 bn = WN[(kt * NTILE + 20 + w) * 64 + lane];
    const f16* ab = hls + kt * 32 + acol8;
#pragma unroll
    for (int m = 0; m < 5; ++m) {
      f16x8 a = *(const f16x8*)(ab + (16 * m + arow) * 168);
      aR[m]  = __builtin_amdgcn_mfma_f32_16x16x32_f16(a, br, aR[m], 0, 0, 0);
      aZ[m]  = __builtin_amdgcn_mfma_f32_16x16x32_f16(a, bz, aZ[m], 0, 0, 0);
      aNh[m] = __builtin_amdgcn_mfma_f32_16x16x32_f16(a, bn, aNh[m], 0, 0, 0);
    }
  }
#pragma unroll
  for (int m = 0; m < 5; ++m) {
#pragma unroll
    for (int q = 0; q < 4; ++q) {
      int row = 16 * m + qrow + q;
      float rg = sigmoid_f(aR[m][q] + bNr);
      float zg = sigmoid_f(aZ[m][q] + bNz);
      float ng = tanh_f(bNi + rg * (aNh[m][q] + bNh));
      float o  = (1.0f - zg) * ng + zg * hp[m][q];
      if (jok) out[(size_t)(t0 + row) * MEMD + j] = o;
    }
  }
}

// ================= fallback: R1 monolithic kernel (proven) =================
namespace fb {

constexpr int BM = 80, NT = 640, XLE_S = 360, XCH_S = 440;
constexpr int KT_L = 11, KT_C = 13, KT_N = 5, NTILE = 30;
constexpr size_t OFF_WL   = 0;
constexpr size_t OFF_WC   = OFF_WL + (size_t)KT_L * NTILE * 64 * 16;
constexpr size_t OFF_WN   = OFF_WC + (size_t)KT_C * NTILE * 64 * 16;
constexpr size_t OFF_BIAS = OFF_WN + (size_t)KT_N * NTILE * 64 * 16;

__global__ void prep_kernel(const float* __restrict__ w_ih_leaf,
                            const float* __restrict__ b_ih_leaf,
                            const float* __restrict__ b_hh_leaf,
                            const float* __restrict__ w_ih_child,
                            const float* __restrict__ w_hh_child,
                            const float* __restrict__ b_ih_child,
                            const float* __restrict__ b_hh_child,
                            const float* __restrict__ w_hh_node,
                            const float* __restrict__ b_ih_node,
                            const float* __restrict__ b_hh_node,
                            char* __restrict__ ws) {
  const int NWL = KT_L * NTILE * 64, NWC = KT_C * NTILE * 64, NWN = KT_N * NTILE * 64;
  int t = blockIdx.x * blockDim.x + threadIdx.x;
  if (t < NWL) {
    int kt = t / (NTILE * 64), rem = t % (NTILE * 64);
    int nt = rem / 64, l = rem % 64;
    int gate = nt / 10, jt = nt % 10;
    int j = jt * 16 + (l & 15);
    bool valid = j < MEMD;
    int g = gate * MEMD + (valid ? j : 0);
    f16x8 v;
#pragma unroll
    for (int e = 0; e < 8; ++e) {
      int k = kt * 32 + ((l >> 4) * 8) + e;
      v[e] = (f16)((valid && k < WORD + TAGD) ? w_ih_leaf[g * (WORD + TAGD) + k] : 0.0f);
    }
    ((f16x8*)(ws + OFF_WL))[t] = v;
    return;
  }
  t -= NWL;
  if (t < NWC) {
    int kt = t / (NTILE * 64), rem = t % (NTILE * 64);
    int nt = rem / 64, l = rem % 64;
    int gate = nt / 10, jt = nt % 10;
    int j = jt * 16 + (l & 15);
    bool valid = j < MEMD;
    int g = gate * MEMD + (valid ? j : 0);
    f16x8 v;
#pragma unroll
    for (int e = 0; e < 8; ++e) {
      int k = kt * 32 + ((l >> 4) * 8) + e;
      float x = 0.0f;
      if (valid) {
        if (k < 250)                  x = w_ih_child[g * 250 + k];
        else if (k >= 256 && k < 406) x = w_hh_child[g * MEMD + (k - 256)];
      }
      v[e] = (f16)x;
    }
    ((f16x8*)(ws + OFF_WC))[t] = v;
    return;
  }
  t -= NWC;
  if (t < NWN) {
    int kt = t / (NTILE * 64), rem = t % (NTILE * 64);
    int nt = rem / 64, l = rem % 64;
    int gate = nt / 10, jt = nt % 10;
    int j = jt * 16 + (l & 15);
    bool valid = j < MEMD;
    int g = gate * MEMD + (valid ? j : 0);
    f16x8 v;
#pragma unroll
    for (int e = 0; e < 8; ++e) {
      int k = kt * 32 + ((l >> 4) * 8) + e;
      v[e] = (f16)((valid && k < MEMD) ? w_hh_node[g * MEMD + k] : 0.0f);
    }
    ((f16x8*)(ws + OFF_WN))[t] = v;
    return;
  }
  t -= NWN;
  if (t < 12 * 160) {
    int arr = t / 160, j = t % 160;
    float v = 0.0f;
    if (j < MEMD) {
      switch (arr) {
        case 0:  v = b_ih_leaf[j] + b_hh_leaf[j]; break;
        case 1:  v = b_ih_leaf[MEMD + j] + b_hh_leaf[MEMD + j]; break;
        case 2:  v = b_ih_leaf[2 * MEMD + j]; break;
        case 3:  v = b_hh_leaf[2 * MEMD + j]; break;
        case 4:  v = b_ih_child[j] + b_hh_child[j]; break;
        case 5:  v = b_ih_child[MEMD + j] + b_hh_child[MEMD + j]; break;
        case 6:  v = b_ih_child[2 * MEMD + j]; break;
        case 7:  v = b_hh_child[2 * MEMD + j]; break;
        case 8:  v = b_ih_node[j] + b_hh_node[j]; break;
        case 9:  v = b_ih_node[MEMD + j] + b_hh_node[MEMD + j]; break;
        case 10: v = b_ih_node[2 * MEMD + j]; break;
        case 11: v = b_hh_node[2 * MEMD + j]; break;
      }
    }
    ((float*)(ws + OFF_BIAS))[arr * 160 + j] = v;
  }
}

__global__ __launch_bounds__(NT, 1)
void gru_tree_mfma(const float* __restrict__ embs,
                   const float* __restrict__ tags,
                   const float* __restrict__ tag_parent,
                   const char*  __restrict__ ws,
                   float* __restrict__ out) {
  extern __shared__ char smem[];
  f16* xle = (f16*)smem;
  f16* xch = xle + BM * XLE_S;
  const f16x8* WL = (const f16x8*)(ws + OFF_WL);
  const f16x8* WC = (const f16x8*)(ws + OFF_WC);
  const f16x8* WN = (const f16x8*)(ws + OFF_WN);
  const float* BIAS = (const float*)(ws + OFF_BIAS);
  const int tid = threadIdx.x, lane = tid & 63, w = tid >> 6;
  const int b0 = blockIdx.x * BM;
  const int arow = lane & 15, acol8 = (lane >> 4) * 8, qrow = (lane >> 4) * 4;
  const int j = w * 16 + (lane & 15);
  const bool jok = (j < MEMD);
  const float bLr = BIAS[0 * 160 + j], bLz = BIAS[1 * 160 + j];
  const float bLi = BIAS[2 * 160 + j], bLh = BIAS[3 * 160 + j];
  const float bCr = BIAS[4 * 160 + j], bCz = BIAS[5 * 160 + j];
  const float bCi = BIAS[6 * 160 + j], bCh = BIAS[7 * 160 + j];
  const float bNr = BIAS[8 * 160 + j], bNz = BIAS[9 * 160 + j];
  const float bNi = BIAS[10 * 160 + j], bNh = BIAS[11 * 160 + j];

  for (int i = tid; i < BM * 190; i += NT) {
    int r = i / 190, cc = i % 190;
    xch[r * XCH_S + 250 + cc] = (f16)0.0f;
  }
  for (int i = tid; i < BM * TAGD; i += NT) {
    int r = i / TAGD, tix = i % TAGD;
    xch[r * XCH_S + 200 + tix] = (f16)tag_parent[(size_t)(b0 + r) * TAGD + tix];
  }

  f32x4 aR[5], aZ[5], aNi[5], aNh[5];
  for (int c = 0; c < CCH; ++c) {
    for (int i = tid; i < BM * (XLE_S / 2); i += NT) {
      int r = i / (XLE_S / 2), k2 = i % (XLE_S / 2);
      int k = k2 * 2;
      size_t row = (size_t)(b0 + r) * CCH + c;
      float2 v;
      if (k < WORD)             v = *(const float2*)(embs + row * WORD + k);
      else if (k < WORD + TAGD) v = *(const float2*)(tags + row * TAGD + (k - WORD));
      else                      v = make_float2(0.0f, 0.0f);
      xle[r * XLE_S + k]     = (f16)v.x;
      xle[r * XLE_S + k + 1] = (f16)v.y;
    }
    for (int i = tid; i < BM * TAGD; i += NT) {
      int r = i / TAGD, tix = i % TAGD;
      xch[r * XCH_S + MEMD + tix] = (f16)tags[((size_t)(b0 + r) * CCH + c) * TAGD + tix];
    }
    __syncthreads();
#pragma unroll
    for (int m = 0; m < 5; ++m) { aR[m] = 0.f; aZ[m] = 0.f; aNi[m] = 0.f; }
    for (int kt = 0; kt < KT_L; ++kt) {
      f16x8 br = WL[(kt * NTILE + w) * 64 + lane];
      f16x8 bz = WL[(kt * NTILE + 10 + w) * 64 + lane];
      f16x8 bn = WL[(kt * NTILE + 20 + w) * 64 + lane];
      const f16* abase = xle + kt * 32 + acol8;
#pragma unroll
      for (int m = 0; m < 5; ++m) {
        f16x8 a = *(const f16x8*)(abase + (16 * m + arow) * XLE_S);
        aR[m]  = __builtin_amdgcn_mfma_f32_16x16x32_f16(a, br, aR[m], 0, 0, 0);
        aZ[m]  = __builtin_amdgcn_mfma_f32_16x16x32_f16(a, bz, aZ[m], 0, 0, 0);
        aNi[m] = __builtin_amdgcn_mfma_f32_16x16x32_f16(a, bn, aNi[m], 0, 0, 0);
      }
    }
#pragma unroll
    for (int m = 0; m < 5; ++m) {
#pragma unroll
      for (int q = 0; q < 4; ++q) {
        float rg = sigmoid_f(aR[m][q] + bLr);
        float zg = sigmoid_f(aZ[m][q] + bLz);
        float ng = tanh_f(aNi[m][q] + bLi + rg * bLh);
        float h  = (1.0f - zg) * ng;
        if (jok) xch[(16 * m + qrow + q) * XCH_S + j] = (f16)h;
      }
    }
    __syncthreads();
#pragma unroll
    for (int m = 0; m < 5; ++m) { aR[m] = 0.f; aZ[m] = 0.f; aNi[m] = 0.f; aNh[m] = 0.f; }
    for (int kt = 0; kt < KT_C; ++kt) {
      f16x8 br = WC[(kt * NTILE + w) * 64 + lane];
      f16x8 bz = WC[(kt * NTILE + 10 + w) * 64 + lane];
      f16x8 bn = WC[(kt * NTILE + 20 + w) * 64 + lane];
      const f16* abase = xch + kt * 32 + acol8;
#pragma unroll
      for (int m = 0; m < 5; ++m) {
        f16x8 a = *(const f16x8*)(abase + (16 * m + arow) * XCH_S);
        aR[m] = __builtin_amdgcn_mfma_f32_16x16x32_f16(a, br, aR[m], 0, 0, 0);
        aZ[m] = __builtin_amdgcn_mfma_f32_16x16x32_f16(a, bz, aZ[m], 0, 0, 0);
        if (kt < 8) aNi[m] = __builtin_amdgcn_mfma_f32_16x16x32_f16(a, bn, aNi[m], 0, 0, 0);
        else        aNh[m] = __builtin_amdgcn_mfma_f32_16x16x32_f16(a, bn, aNh[m], 0, 0, 0);
      }
    }
    __syncthreads();
#pragma unroll
    for (int m = 0; m < 5; ++m) {
#pragma unroll
      for (int q = 0; q < 4; ++q) {
        int row = 16 * m + qrow + q;
        float hp = (float)xch[row * XCH_S + 256 + j];
        float rg = sigmoid_f(aR[m][q] + bCr);
        float zg = sigmoid_f(aZ[m][q] + bCz);
        float ng = tanh_f(aNi[m][q] + bCi + rg * (aNh[m][q] + bCh));
        float h  = (1.0f - zg) * ng + zg * hp;
        if (jok) xch[row * XCH_S + 256 + j] = (f16)h;
      }
    }
  }
  __syncthreads();
#pragma unroll
  for (int m = 0; m < 5; ++m) { aR[m] = 0.f; aZ[m] = 0.f; aNh[m] = 0.f; }
  for (int kt = 0; kt < KT_N; ++kt) {
    f16x8 br = WN[(kt * NTILE + w) * 64 + lane];
    f16x8 bz = WN[(kt * NTILE + 10 + w) * 64 + lane];
    f16x8 bn = WN[(kt * NTILE + 20 + w) * 64 + lane];
    const f16* abase = xch + 256 + kt * 32 + acol8;
#pragma unroll
    for (int m = 0; m < 5; ++m) {
      f16x8 a = *(const f16x8*)(abase + (16 * m + arow) * XCH_S);
      aR[m]  = __builtin_amdgcn_mfma_f32_16x16x32_f16(a, br, aR[m], 0, 0, 0);
      aZ[m]  = __builtin_amdgcn_mfma_f32_16x16x32_f16(a, bz, aZ[m], 0, 0, 0);
      aNh[m] = __builtin_amdgcn_mfma_f32_16x16x32_f16(a, bn, aNh[m], 0, 0, 0);
    }
  }
#pragma unroll
  for (int m = 0; m < 5; ++m) {
#pragma unroll
    for (int q = 0; q < 4; ++q) {
      int row = 16 * m + qrow + q;
      float hp = (float)xch[row * XCH_S + 256 + j];
      float rg = sigmoid_f(aR[m][q] + bNr);
      float zg = sigmoid_f(aZ[m][q] + bNz);
      float ng = tanh_f(bNi + rg * (aNh[m][q] + bNh));
      float o  = (1.0f - zg) * ng + zg * hp;
      if (jok) out[(size_t)(b0 + row) * MEMD + j] = o;
    }
  }
}

}  // namespace fb

}  // namespace

extern "C" void kernel_launch(void* const* d_in, const int* in_sizes, int n_in,
                              void* d_out, int out_size, void* d_ws, size_t ws_size,
                              hipStream_t stream) {
  const float* embs       = (const float*)d_in[0];
  const float* tags       = (const float*)d_in[1];
  const float* tag_parent = (const float*)d_in[2];
  const float* w_ih_leaf  = (const float*)d_in[3];
  // d_in[4] w_hh_leaf unused (h0 = 0)
  const float* b_ih_leaf  = (const float*)d_in[5];
  const float* b_hh_leaf  = (const float*)d_in[6];
  const float* w_ih_child = (const float*)d_in[7];
  const float* w_hh_child = (const float*)d_in[8];
  const float* b_ih_child = (const float*)d_in[9];
  const float* b_hh_child = (const float*)d_in[10];
  // d_in[11] w_ih_node unused (x = 0)
  const float* w_hh_node  = (const float*)d_in[12];
  const float* b_ih_node  = (const float*)d_in[13];
  const float* b_hh_node  = (const float*)d_in[14];
  float* out = (float*)d_out;
  char*  ws  = (char*)d_ws;

  if (ws_size >= WS_NEED) {
    prep2_kernel<<<225, 256, 0, stream>>>(w_ih_leaf, b_ih_leaf, b_hh_leaf,
                                          w_ih_child, w_hh_child, b_ih_child, b_hh_child,
                                          w_hh_node, b_ih_node, b_hh_node, ws);
    leaf_kernel<<<dim3(250, 8), 640, 0, stream>>>(embs, tags, ws);
    constexpr int FOLD_LDS = (2 * 80 * 264 + 80 * 168) * 2;  // 111360
    hipFuncSetAttribute((const void*)fold_kernel,
                        hipFuncAttributeMaxDynamicSharedMemorySize, FOLD_LDS);
    fold_kernel<<<250, 640, FOLD_LDS, stream>>>(tags, tag_parent, ws, out);
  } else {
    fb::prep_kernel<<<225, 256, 0, stream>>>(w_ih_leaf, b_ih_leaf, b_hh_leaf,
                                             w_ih_child, w_hh_child, b_ih_child, b_hh_child,
                                             w_hh_node, b_ih_node, b_hh_node, ws);
    constexpr int LDS_BYTES = (fb::BM * fb::XLE_S + fb::BM * fb::XCH_S) * 2;  // 128000
    hipFuncSetAttribute((const void*)fb::gru_tree_mfma,
                        hipFuncAttributeMaxDynamicSharedMemorySize, LDS_BYTES);
    fb::gru_tree_mfma<<<NTREE / fb::BM, fb::NT, LDS_BYTES, stream>>>(
        embs, tags, tag_parent, ws, out);
  }
}

// Round 4
// 448.255 us; speedup vs baseline: 8.7453x; 1.0482x over previous
//
#include <hip/hip_runtime.h>

// FasterGRUTree R3: precompute child-GRU input preactivations (gi) in the parallel
// leaf phase, stored fragment-ordered so the serial fold reads them register-direct.
//  prep_kernel:  fp32 weights -> f16 fragment-ordered B operands + 16 bias tables.
//  leaf3_kernel: (250,8) blocks: leaf GRU + x_child@W_ih_child^T -> gi (f16, ws).
//  fold3_kernel: 250 blocks: 8-step fold = gh GEMM (K=160) + gates; node GRU; out.
// Fallback (ws too small): R2 split kernels (proven, 470 us).

typedef _Float16 f16;
typedef _Float16 f16x4 __attribute__((ext_vector_type(4)));
typedef _Float16 f16x8 __attribute__((ext_vector_type(8)));
typedef float f32x4 __attribute__((ext_vector_type(4)));

namespace {

constexpr int NTREE = 20000;
constexpr int CCH   = 8;
constexpr int WORD  = 300;
constexpr int TAGD  = 50;
constexpr int MEMD  = 150;
constexpr int NBLK  = 250;   // tree-group blocks (80 trees each)

constexpr int KT_L = 11;     // leaf K tiles (352)
constexpr int KT_I = 8;      // x_child K tiles (256 = h|00|tag|tagp|0^4)
constexpr int KT_H = 5;      // hh K tiles (160)
constexpr int KT_N = 5;      // node K tiles (160)
constexpr int NTILE = 30;    // 3 gates x 10 j-tiles

constexpr size_t OFF_WL   = 0;
constexpr size_t OFF_WI   = OFF_WL + (size_t)KT_L * NTILE * 64 * 16;  // 337920
constexpr size_t OFF_WH   = OFF_WI + (size_t)KT_I * NTILE * 64 * 16;  // 583680
constexpr size_t OFF_WN   = OFF_WH + (size_t)KT_H * NTILE * 64 * 16;  // 737280
constexpr size_t OFF_BIAS = OFF_WN + (size_t)KT_N * NTILE * 64 * 16;  // 890880
constexpr size_t OFF_DATA = OFF_BIAS + 16 * 160 * 4;                  // 901120

// R3 gi region: [c][blk][unit 0..14][tid 0..639] * 8B
constexpr size_t GI_BYTES = (size_t)CCH * NBLK * 15 * 640 * 8;        // 153,600,000
constexpr size_t WS_R3    = OFF_DATA + GI_BYTES;                      // 154,501,120
// R2 h region: [c][tree][152] f16
constexpr int    HW_S  = 152;
constexpr size_t WS_R2 = OFF_DATA + (size_t)CCH * NTREE * HW_S * 2;   // 49,541,120

// BIAS arrays (16 x 160 f32):
//  0 bL_r(ih+hh) 1 bL_z(ih+hh) 2 bL_in(ih) 3 bL_hn(hh)
//  4 bC_r(ih+hh) 5 bC_z(ih+hh) 6 bC_in(ih) 7 bC_hn(hh)
//  8 bN_r(ih+hh) 9 bN_z(ih+hh) 10 bN_in(ih) 11 bN_hn(hh)
// 12 bC_ir(ih) 13 bC_iz(ih) 14 bC_hr(hh) 15 bC_hz(hh)

__device__ __forceinline__ float sigmoid_f(float x) {
  return 1.0f / (1.0f + __expf(-x));
}
__device__ __forceinline__ float tanh_f(float x) {
  float ax = fabsf(x);
  float e  = __expf(-2.0f * ax);
  float t  = (1.0f - e) / (1.0f + e);
  return copysignf(t, x);
}

// ---------------- prep ----------------
__global__ void prep_kernel(const float* __restrict__ w_ih_leaf,
                            const float* __restrict__ b_ih_leaf,
                            const float* __restrict__ b_hh_leaf,
                            const float* __restrict__ w_ih_child,
                            const float* __restrict__ w_hh_child,
                            const float* __restrict__ b_ih_child,
                            const float* __restrict__ b_hh_child,
                            const float* __restrict__ w_hh_node,
                            const float* __restrict__ b_ih_node,
                            const float* __restrict__ b_hh_node,
                            char* __restrict__ ws) {
  const int NWL = KT_L * NTILE * 64;  // 21120
  const int NWI = KT_I * NTILE * 64;  // 15360
  const int NWH = KT_H * NTILE * 64;  //  9600
  const int NWN = KT_N * NTILE * 64;  //  9600
  int t = blockIdx.x * blockDim.x + threadIdx.x;

  if (t < NWL) {  // w_ih_leaf, K=352
    int kt = t / (NTILE * 64), rem = t % (NTILE * 64);
    int nt = rem / 64, l = rem % 64;
    int gate = nt / 10, jt = nt % 10;
    int j = jt * 16 + (l & 15);
    bool valid = j < MEMD;
    int g = gate * MEMD + (valid ? j : 0);
    f16x8 v;
#pragma unroll
    for (int e = 0; e < 8; ++e) {
      int k = kt * 32 + ((l >> 4) * 8) + e;
      v[e] = (f16)((valid && k < WORD + TAGD) ? w_ih_leaf[g * (WORD + TAGD) + k] : 0.0f);
    }
    ((f16x8*)(ws + OFF_WL))[t] = v;
    return;
  }
  t -= NWL;
  if (t < NWI) {  // w_ih_child remapped: k<150 state | 150,151 z | 152..201 tag | 202..251 tagp | 252..255 z
    int kt = t / (NTILE * 64), rem = t % (NTILE * 64);
    int nt = rem / 64, l = rem % 64;
    int gate = nt / 10, jt = nt % 10;
    int j = jt * 16 + (l & 15);
    bool valid = j < MEMD;
    int g = gate * MEMD + (valid ? j : 0);
    f16x8 v;
#pragma unroll
    for (int e = 0; e < 8; ++e) {
      int k = kt * 32 + ((l >> 4) * 8) + e;
      int src = (k < 150) ? k : (k >= 152 && k < 252) ? (k - 2) : -1;
      v[e] = (f16)((valid && src >= 0) ? w_ih_child[g * 250 + src] : 0.0f);
    }
    ((f16x8*)(ws + OFF_WI))[t] = v;
    return;
  }
  t -= NWI;
  if (t < NWH) {  // w_hh_child, K=160
    int kt = t / (NTILE * 64), rem = t % (NTILE * 64);
    int nt = rem / 64, l = rem % 64;
    int gate = nt / 10, jt = nt % 10;
    int j = jt * 16 + (l & 15);
    bool valid = j < MEMD;
    int g = gate * MEMD + (valid ? j : 0);
    f16x8 v;
#pragma unroll
    for (int e = 0; e < 8; ++e) {
      int k = kt * 32 + ((l >> 4) * 8) + e;
      v[e] = (f16)((valid && k < MEMD) ? w_hh_child[g * MEMD + k] : 0.0f);
    }
    ((f16x8*)(ws + OFF_WH))[t] = v;
    return;
  }
  t -= NWH;
  if (t < NWN) {  // w_hh_node, K=160
    int kt = t / (NTILE * 64), rem = t % (NTILE * 64);
    int nt = rem / 64, l = rem % 64;
    int gate = nt / 10, jt = nt % 10;
    int j = jt * 16 + (l & 15);
    bool valid = j < MEMD;
    int g = gate * MEMD + (valid ? j : 0);
    f16x8 v;
#pragma unroll
    for (int e = 0; e < 8; ++e) {
      int k = kt * 32 + ((l >> 4) * 8) + e;
      v[e] = (f16)((valid && k < MEMD) ? w_hh_node[g * MEMD + k] : 0.0f);
    }
    ((f16x8*)(ws + OFF_WN))[t] = v;
    return;
  }
  t -= NWN;
  if (t < 16 * 160) {
    int arr = t / 160, j = t % 160;
    float v = 0.0f;
    if (j < MEMD) {
      switch (arr) {
        case 0:  v = b_ih_leaf[j] + b_hh_leaf[j]; break;
        case 1:  v = b_ih_leaf[MEMD + j] + b_hh_leaf[MEMD + j]; break;
        case 2:  v = b_ih_leaf[2 * MEMD + j]; break;
        case 3:  v = b_hh_leaf[2 * MEMD + j]; break;
        case 4:  v = b_ih_child[j] + b_hh_child[j]; break;
        case 5:  v = b_ih_child[MEMD + j] + b_hh_child[MEMD + j]; break;
        case 6:  v = b_ih_child[2 * MEMD + j]; break;
        case 7:  v = b_hh_child[2 * MEMD + j]; break;
        case 8:  v = b_ih_node[j] + b_hh_node[j]; break;
        case 9:  v = b_ih_node[MEMD + j] + b_hh_node[MEMD + j]; break;
        case 10: v = b_ih_node[2 * MEMD + j]; break;
        case 11: v = b_hh_node[2 * MEMD + j]; break;
        case 12: v = b_ih_child[j]; break;
        case 13: v = b_ih_child[MEMD + j]; break;
        case 14: v = b_hh_child[j]; break;
        case 15: v = b_hh_child[MEMD + j]; break;
      }
    }
    ((float*)(ws + OFF_BIAS))[arr * 160 + j] = v;
  }
}

// ---------------- R3 leaf: leaf GRU + gi = x_child @ W_ih_child^T + b_ih ----------------
__global__ __launch_bounds__(640, 2)
void leaf3_kernel(const float* __restrict__ embs,
                  const float* __restrict__ tags,
                  const float* __restrict__ tag_parent,
                  char* __restrict__ ws) {
  extern __shared__ char lsm[];
  f16* xle = (f16*)lsm;            // [80][360]  57600 B
  f16* xch = xle + 80 * 360;       // [80][264]  42240 B

  const f16x8* WL   = (const f16x8*)(ws + OFF_WL);
  const f16x8* WI   = (const f16x8*)(ws + OFF_WI);
  const float* BIAS = (const float*)(ws + OFF_BIAS);

  const int tid = threadIdx.x, lane = tid & 63, w = tid >> 6;
  const int blk = blockIdx.x, c = blockIdx.y, t0 = blk * 80;
  const int arow = lane & 15, acol8 = (lane >> 4) * 8, qrow = (lane >> 4) * 4;
  const int j = w * 16 + arow;
  const bool jok = j < MEMD;

  // stage x_leaf = [emb|tag|00]
  for (int i = tid; i < 80 * 150; i += 640) {
    int r = i / 150, k2 = i - r * 150;
    float2 v = *(const float2*)(embs + ((size_t)(t0 + r) * CCH + c) * WORD + 2 * k2);
    xle[r * 360 + 2 * k2]     = (f16)v.x;
    xle[r * 360 + 2 * k2 + 1] = (f16)v.y;
  }
  for (int i = tid; i < 80 * 25; i += 640) {
    int r = i / 25, k2 = i - r * 25;
    float2 v = *(const float2*)(tags + ((size_t)(t0 + r) * CCH + c) * TAGD + 2 * k2);
    xle[r * 360 + 300 + 2 * k2]     = (f16)v.x;
    xle[r * 360 + 300 + 2 * k2 + 1] = (f16)v.y;
  }
  // stage x_child fixed parts: tagp cols 202..252; zero cols {150,151,252..263}; xle pad
  for (int i = tid; i < 80 * 25; i += 640) {
    int r = i / 25, k2 = i - r * 25;
    float2 v = *(const float2*)(tag_parent + (size_t)(t0 + r) * TAGD + 2 * k2);
    xch[r * 264 + 202 + 2 * k2] = (f16)v.x;
    xch[r * 264 + 203 + 2 * k2] = (f16)v.y;
  }
  for (int i = tid; i < 80 * 14; i += 640) {
    int r = i / 14, k = i - r * 14;
    int col = (k < 2) ? (150 + k) : (250 + k);  // 150,151,252..263
    xch[r * 264 + col] = (f16)0.0f;
  }
  for (int i = tid; i < 80; i += 640) {
    xle[i * 360 + 350] = (f16)0.0f;
    xle[i * 360 + 351] = (f16)0.0f;
  }
  __syncthreads();

  // tag copy LDS->LDS (xle stable now): cols 152..202 of xch
  for (int i = tid; i < 80 * 50; i += 640) {
    int r = i / 50, tt = i - r * 50;
    xch[r * 264 + 152 + tt] = xle[r * 360 + 300 + tt];
  }

  // leaf GEMM K=352
  f32x4 aR[5], aZ[5], aN[5];
#pragma unroll
  for (int m = 0; m < 5; ++m) { aR[m] = 0.f; aZ[m] = 0.f; aN[m] = 0.f; }
  for (int kt = 0; kt < KT_L; ++kt) {
    f16x8 br = WL[(kt * NTILE + w) * 64 + lane];
    f16x8 bz = WL[(kt * NTILE + 10 + w) * 64 + lane];
    f16x8 bn = WL[(kt * NTILE + 20 + w) * 64 + lane];
    const f16* ab = xle + kt * 32 + acol8;
#pragma unroll
    for (int m = 0; m < 5; ++m) {
      f16x8 a = *(const f16x8*)(ab + (16 * m + arow) * 360);
      aR[m] = __builtin_amdgcn_mfma_f32_16x16x32_f16(a, br, aR[m], 0, 0, 0);
      aZ[m] = __builtin_amdgcn_mfma_f32_16x16x32_f16(a, bz, aZ[m], 0, 0, 0);
      aN[m] = __builtin_amdgcn_mfma_f32_16x16x32_f16(a, bn, aN[m], 0, 0, 0);
    }
  }

  // leaf gates -> h into xch cols [0,150)
  {
    const float bLr = BIAS[j], bLz = BIAS[160 + j], bLi = BIAS[320 + j], bLh = BIAS[480 + j];
#pragma unroll
    for (int m = 0; m < 5; ++m) {
#pragma unroll
      for (int q = 0; q < 4; ++q) {
        float rg = sigmoid_f(aR[m][q] + bLr);
        float zg = sigmoid_f(aZ[m][q] + bLz);
        float ng = tanh_f(aN[m][q] + bLi + rg * bLh);
        float h  = (1.0f - zg) * ng;  // h0 = 0
        if (jok) xch[(16 * m + qrow + q) * 264 + j] = (f16)h;
      }
    }
  }
  __syncthreads();

  // x-GEMM K=256: gi for this wave's j-tile, 3 gates
  f32x4 cR[5], cZ[5], cN[5];
#pragma unroll
  for (int m = 0; m < 5; ++m) { cR[m] = 0.f; cZ[m] = 0.f; cN[m] = 0.f; }
  for (int kt = 0; kt < KT_I; ++kt) {
    f16x8 br = WI[(kt * NTILE + w) * 64 + lane];
    f16x8 bz = WI[(kt * NTILE + 10 + w) * 64 + lane];
    f16x8 bn = WI[(kt * NTILE + 20 + w) * 64 + lane];
    const f16* ab = xch + kt * 32 + acol8;
#pragma unroll
    for (int m = 0; m < 5; ++m) {
      f16x8 a = *(const f16x8*)(ab + (16 * m + arow) * 264);
      cR[m] = __builtin_amdgcn_mfma_f32_16x16x32_f16(a, br, cR[m], 0, 0, 0);
      cZ[m] = __builtin_amdgcn_mfma_f32_16x16x32_f16(a, bz, cZ[m], 0, 0, 0);
      cN[m] = __builtin_amdgcn_mfma_f32_16x16x32_f16(a, bn, cN[m], 0, 0, 0);
    }
  }

  // bake b_ih_child, pack f16, store fragment-ordered gi (fold reads identically)
  {
    const float bir = BIAS[12 * 160 + j], biz = BIAS[13 * 160 + j], bin = BIAS[6 * 160 + j];
    char* gib = ws + OFF_DATA + ((((size_t)c * NBLK + blk) * 15) * 640 + tid) * 8;
#pragma unroll
    for (int m = 0; m < 5; ++m) {
      f16x4 vr, vz, vn;
#pragma unroll
      for (int q = 0; q < 4; ++q) {
        vr[q] = (f16)(cR[m][q] + bir);
        vz[q] = (f16)(cZ[m][q] + biz);
        vn[q] = (f16)(cN[m][q] + bin);
      }
      *(f16x4*)(gib + (size_t)(m * 3 + 0) * 640 * 8) = vr;
      *(f16x4*)(gib + (size_t)(m * 3 + 1) * 640 * 8) = vz;
      *(f16x4*)(gib + (size_t)(m * 3 + 2) * 640 * 8) = vn;
    }
  }
}

// ---------------- R3 fold: gh GEMM + gates, gi register-direct ----------------
__global__ __launch_bounds__(640, 2)
void fold3_kernel(const char* __restrict__ ws,
                  float* __restrict__ out) {
  __shared__ f16 hls[80 * 168];   // 26880 B

  const f16x8* WH   = (const f16x8*)(ws + OFF_WH);
  const f16x8* WN   = (const f16x8*)(ws + OFF_WN);
  const float* BIAS = (const float*)(ws + OFF_BIAS);

  const int tid = threadIdx.x, lane = tid & 63, w = tid >> 6;
  const int blk = blockIdx.x, t0 = blk * 80;
  const int arow = lane & 15, acol8 = (lane >> 4) * 8, qrow = (lane >> 4) * 4;
  const int j = w * 16 + arow;
  const bool jok = j < MEMD;

  const float bhr = BIAS[14 * 160 + j], bhz = BIAS[15 * 160 + j], bhn = BIAS[7 * 160 + j];
  const float bNr = BIAS[8 * 160 + j],  bNz = BIAS[9 * 160 + j];
  const float bNi = BIAS[10 * 160 + j], bNh = BIAS[11 * 160 + j];

  for (int i = tid; i < 1680; i += 640) ((int4*)hls)[i] = make_int4(0, 0, 0, 0);
  __syncthreads();

  const char* gib = ws + OFF_DATA + ((size_t)blk * 15 * 640 + tid) * 8;
  constexpr size_t CSTRIDE = (size_t)NBLK * 15 * 640 * 8;  // per-child stride

  f16x4 gbuf[2][15];
#pragma unroll
  for (int u = 0; u < 15; ++u)
    gbuf[0][u] = *(const f16x4*)(gib + (size_t)u * 640 * 8);

  f32x4 hp[5];
#pragma unroll
  for (int m = 0; m < 5; ++m) hp[m] = 0.f;

#pragma unroll
  for (int c = 0; c < CCH; ++c) {
    // prefetch gi(c+1) (T14: latency hides under GEMM + gate math)
    if (c < CCH - 1) {
#pragma unroll
      for (int u = 0; u < 15; ++u)
        gbuf[(c + 1) & 1][u] =
            *(const f16x4*)(gib + (size_t)(c + 1) * CSTRIDE + (size_t)u * 640 * 8);
    }

    // gh GEMM K=160 (c=0: h=0 -> result 0, uniform path)
    f32x4 aR[5], aZ[5], aNh[5];
#pragma unroll
    for (int m = 0; m < 5; ++m) { aR[m] = 0.f; aZ[m] = 0.f; aNh[m] = 0.f; }
    for (int kt = 0; kt < KT_H; ++kt) {
      f16x8 br = WH[(kt * NTILE + w) * 64 + lane];
      f16x8 bz = WH[(kt * NTILE + 10 + w) * 64 + lane];
      f16x8 bn = WH[(kt * NTILE + 20 + w) * 64 + lane];
      const f16* ab = hls + kt * 32 + acol8;
#pragma unroll
      for (int m = 0; m < 5; ++m) {
        f16x8 a = *(const f16x8*)(ab + (16 * m + arow) * 168);
        aR[m]  = __builtin_amdgcn_mfma_f32_16x16x32_f16(a, br, aR[m], 0, 0, 0);
        aZ[m]  = __builtin_amdgcn_mfma_f32_16x16x32_f16(a, bz, aZ[m], 0, 0, 0);
        aNh[m] = __builtin_amdgcn_mfma_f32_16x16x32_f16(a, bn, aNh[m], 0, 0, 0);
      }
    }
    __syncthreads();  // B1: all hls reads done

    // gates; h -> regs + LDS
#pragma unroll
    for (int m = 0; m < 5; ++m) {
#pragma unroll
      for (int q = 0; q < 4; ++q) {
        int row = 16 * m + qrow + q;
        float gr = (float)gbuf[c & 1][m * 3 + 0][q];
        float gz = (float)gbuf[c & 1][m * 3 + 1][q];
        float gn = (float)gbuf[c & 1][m * 3 + 2][q];
        float rg = sigmoid_f(gr + aR[m][q] + bhr);
        float zg = sigmoid_f(gz + aZ[m][q] + bhz);
        float ng = tanh_f(gn + rg * (aNh[m][q] + bhn));
        float h  = (1.0f - zg) * ng + zg * hp[m][q];
        hp[m][q] = h;
        if (jok) hls[row * 168 + j] = (f16)h;
      }
    }
    __syncthreads();  // B2: h visible
  }

  // node GRU
  f32x4 aR[5], aZ[5], aNh[5];
#pragma unroll
  for (int m = 0; m < 5; ++m) { aR[m] = 0.f; aZ[m] = 0.f; aNh[m] = 0.f; }
  for (int kt = 0; kt < KT_N; ++kt) {
    f16x8 br = WN[(kt * NTILE + w) * 64 + lane];
    f16x8 bz = WN[(kt * NTILE + 10 + w) * 64 + lane];
    f16x8 bn = WN[(kt * NTILE + 20 + w) * 64 + lane];
    const f16* ab = hls + kt * 32 + acol8;
#pragma unroll
    for (int m = 0; m < 5; ++m) {
      f16x8 a = *(const f16x8*)(ab + (16 * m + arow) * 168);
      aR[m]  = __builtin_amdgcn_mfma_f32_16x16x32_f16(a, br, aR[m], 0, 0, 0);
      aZ[m]  = __builtin_amdgcn_mfma_f32_16x16x32_f16(a, bz, aZ[m], 0, 0, 0);
      aNh[m] = __builtin_amdgcn_mfma_f32_16x16x32_f16(a, bn, aNh[m], 0, 0, 0);
    }
  }
#pragma unroll
  for (int m = 0; m < 5; ++m) {
#pragma unroll
    for (int q = 0; q < 4; ++q) {
      int row = 16 * m + qrow + q;
      float rg = sigmoid_f(aR[m][q] + bNr);
      float zg = sigmoid_f(aZ[m][q] + bNz);
      float ng = tanh_f(bNi + rg * (aNh[m][q] + bNh));
      float o  = (1.0f - zg) * ng + zg * hp[m][q];
      if (jok) out[(size_t)(t0 + row) * MEMD + j] = o;
    }
  }
}

// ================= R2 fallback (proven) =================
namespace r2 {

__global__ __launch_bounds__(640)
void leaf_kernel(const float* __restrict__ embs,
                 const float* __restrict__ tags,
                 char* __restrict__ ws) {
  __shared__ f16 xle[80 * 360];
  const f16x8* WL   = (const f16x8*)(ws + OFF_WL);
  const float* BIAS = (const float*)(ws + OFF_BIAS);
  f16* hws = (f16*)(ws + OFF_DATA);

  const int tid = threadIdx.x, lane = tid & 63, w = tid >> 6;
  const int c = blockIdx.y, t0 = blockIdx.x * 80;
  const int arow = lane & 15, acol8 = (lane >> 4) * 8, qrow = (lane >> 4) * 4;
  const int j = w * 16 + (lane & 15);

  for (int i = tid; i < 80 * 150; i += 640) {
    int r = i / 150, k2 = i - r * 150;
    float2 v = *(const float2*)(embs + ((size_t)(t0 + r) * CCH + c) * WORD + 2 * k2);
    xle[r * 360 + 2 * k2]     = (f16)v.x;
    xle[r * 360 + 2 * k2 + 1] = (f16)v.y;
  }
  for (int i = tid; i < 80 * 25; i += 640) {
    int r = i / 25, k2 = i - r * 25;
    float2 v = *(const float2*)(tags + ((size_t)(t0 + r) * CCH + c) * TAGD + 2 * k2);
    xle[r * 360 + 300 + 2 * k2]     = (f16)v.x;
    xle[r * 360 + 300 + 2 * k2 + 1] = (f16)v.y;
  }
  for (int i = tid; i < 80; i += 640) {
    xle[i * 360 + 350] = (f16)0.0f;
    xle[i * 360 + 351] = (f16)0.0f;
  }
  __syncthreads();

  f32x4 aR[5], aZ[5], aN[5];
#pragma unroll
  for (int m = 0; m < 5; ++m) { aR[m] = 0.f; aZ[m] = 0.f; aN[m] = 0.f; }
  for (int kt = 0; kt < KT_L; ++kt) {
    f16x8 br = WL[(kt * NTILE + w) * 64 + lane];
    f16x8 bz = WL[(kt * NTILE + 10 + w) * 64 + lane];
    f16x8 bn = WL[(kt * NTILE + 20 + w) * 64 + lane];
    const f16* ab = xle + kt * 32 + acol8;
#pragma unroll
    for (int m = 0; m < 5; ++m) {
      f16x8 a = *(const f16x8*)(ab + (16 * m + arow) * 360);
      aR[m] = __builtin_amdgcn_mfma_f32_16x16x32_f16(a, br, aR[m], 0, 0, 0);
      aZ[m] = __builtin_amdgcn_mfma_f32_16x16x32_f16(a, bz, aZ[m], 0, 0, 0);
      aN[m] = __builtin_amdgcn_mfma_f32_16x16x32_f16(a, bn, aN[m], 0, 0, 0);
    }
  }
  const float bLr = BIAS[j], bLz = BIAS[160 + j], bLi = BIAS[320 + j], bLh = BIAS[480 + j];
#pragma unroll
  for (int m = 0; m < 5; ++m) {
#pragma unroll
    for (int q = 0; q < 4; ++q) {
      int row = 16 * m + qrow + q;
      float rg = sigmoid_f(aR[m][q] + bLr);
      float zg = sigmoid_f(aZ[m][q] + bLz);
      float ng = tanh_f(aN[m][q] + bLi + rg * bLh);
      float h  = (1.0f - zg) * ng;
      if (j < HW_S)
        hws[((size_t)c * NTREE + t0 + row) * HW_S + j] = (f16)(j < MEMD ? h : 0.0f);
    }
  }
}

__global__ __launch_bounds__(640)
void fold_kernel(const float* __restrict__ tags,
                 const float* __restrict__ tag_parent,
                 const char* __restrict__ ws,
                 float* __restrict__ out) {
  extern __shared__ char fsm[];
  f16* xch0 = (f16*)fsm;
  f16* xch1 = xch0 + 80 * 264;
  f16* hls  = xch1 + 80 * 264;

  const f16x8* WI   = (const f16x8*)(ws + OFF_WI);
  const f16x8* WH   = (const f16x8*)(ws + OFF_WH);
  const f16x8* WN   = (const f16x8*)(ws + OFF_WN);
  const float* BIAS = (const float*)(ws + OFF_BIAS);
  const f16*   hws  = (const f16*)(ws + OFF_DATA);

  const int tid = threadIdx.x, lane = tid & 63, w = tid >> 6;
  const int t0 = blockIdx.x * 80;
  const int arow = lane & 15, acol8 = (lane >> 4) * 8, qrow = (lane >> 4) * 4;
  const int j = w * 16 + (lane & 15);
  const bool jok = j < MEMD;

  const float bCr = BIAS[4 * 160 + j], bCz = BIAS[5 * 160 + j];
  const float bCi = BIAS[6 * 160 + j], bCh = BIAS[7 * 160 + j];
  const float bNr = BIAS[8 * 160 + j], bNz = BIAS[9 * 160 + j];
  const float bNi = BIAS[10 * 160 + j], bNh = BIAS[11 * 160 + j];

  for (int i = tid; i < 1680; i += 640) ((int4*)hls)[i] = make_int4(0, 0, 0, 0);
  for (int i = tid; i < 80 * 25; i += 640) {
    int r = i / 25, k2 = i - r * 25;
    float2 v = *(const float2*)(tag_parent + (size_t)(t0 + r) * TAGD + 2 * k2);
    f16 a = (f16)v.x, b = (f16)v.y;
    xch0[r * 264 + 202 + 2 * k2] = a; xch0[r * 264 + 203 + 2 * k2] = b;
    xch1[r * 264 + 202 + 2 * k2] = a; xch1[r * 264 + 203 + 2 * k2] = b;
  }
  for (int i = tid; i < 80 * 4; i += 640) {
    int r = i >> 2, k = i & 3;
    xch0[r * 264 + 252 + k] = (f16)0.0f;
    xch1[r * 264 + 252 + k] = (f16)0.0f;
  }
#pragma unroll
  for (int s = 0; s < 3; ++s) {
    int i = tid + 640 * s;
    if (i < 1520) {
      int r = i / 19, q = i - r * 19;
      *(f16x8*)(xch0 + r * 264 + 8 * q) =
          *(const f16x8*)(hws + ((size_t)(t0 + r)) * HW_S + 8 * q);
    }
  }
#pragma unroll
  for (int s = 0; s < 4; ++s) {
    int i = tid + 640 * s;
    if (i < 2000) {
      int r = i / 25, k2 = i - r * 25;
      float2 v = *(const float2*)(tags + ((size_t)(t0 + r) * CCH) * TAGD + 2 * k2);
      xch0[r * 264 + 152 + 2 * k2] = (f16)v.x;
      xch0[r * 264 + 153 + 2 * k2] = (f16)v.y;
    }
  }
  __syncthreads();

  f32x4 hp[5];
#pragma unroll
  for (int m = 0; m < 5; ++m) hp[m] = 0.f;

  f16* xc = xch0;
  f16* xa = xch1;

  for (int c = 0; c < CCH; ++c) {
    f16x8 ph[3];
    float2 pt[4];
    if (c < 7) {
#pragma unroll
      for (int s = 0; s < 3; ++s) {
        int i = tid + 640 * s;
        if (i < 1520) {
          int r = i / 19, q = i - r * 19;
          ph[s] = *(const f16x8*)(hws + ((size_t)(c + 1) * NTREE + t0 + r) * HW_S + 8 * q);
        }
      }
#pragma unroll
      for (int s = 0; s < 4; ++s) {
        int i = tid + 640 * s;
        if (i < 2000) {
          int r = i / 25, k2 = i - r * 25;
          pt[s] = *(const float2*)(tags + ((size_t)(t0 + r) * CCH + (c + 1)) * TAGD + 2 * k2);
        }
      }
    }

    f32x4 aR[5], aZ[5], aNi[5], aNh[5];
#pragma unroll
    for (int m = 0; m < 5; ++m) { aR[m] = 0.f; aZ[m] = 0.f; aNi[m] = 0.f; aNh[m] = 0.f; }
    for (int kt = 0; kt < KT_I; ++kt) {
      f16x8 br = WI[(kt * NTILE + w) * 64 + lane];
      f16x8 bz = WI[(kt * NTILE + 10 + w) * 64 + lane];
      f16x8 bn = WI[(kt * NTILE + 20 + w) * 64 + lane];
      const f16* ab = xc + kt * 32 + acol8;
#pragma unroll
      for (int m = 0; m < 5; ++m) {
        f16x8 a = *(const f16x8*)(ab + (16 * m + arow) * 264);
        aR[m]  = __builtin_amdgcn_mfma_f32_16x16x32_f16(a, br, aR[m], 0, 0, 0);
        aZ[m]  = __builtin_amdgcn_mfma_f32_16x16x32_f16(a, bz, aZ[m], 0, 0, 0);
        aNi[m] = __builtin_amdgcn_mfma_f32_16x16x32_f16(a, bn, aNi[m], 0, 0, 0);
      }
    }
    for (int kt = 0; kt < KT_H; ++kt) {
      f16x8 br = WH[(kt * NTILE + w) * 64 + lane];
      f16x8 bz = WH[(kt * NTILE + 10 + w) * 64 + lane];
      f16x8 bn = WH[(kt * NTILE + 20 + w) * 64 + lane];
      const f16* ab = hls + kt * 32 + acol8;
#pragma unroll
      for (int m = 0; m < 5; ++m) {
        f16x8 a = *(const f16x8*)(ab + (16 * m + arow) * 168);
        aR[m]  = __builtin_amdgcn_mfma_f32_16x16x32_f16(a, br, aR[m], 0, 0, 0);
        aZ[m]  = __builtin_amdgcn_mfma_f32_16x16x32_f16(a, bz, aZ[m], 0, 0, 0);
        aNh[m] = __builtin_amdgcn_mfma_f32_16x16x32_f16(a, bn, aNh[m], 0, 0, 0);
      }
    }
    __syncthreads();

    if (c < 7) {
#pragma unroll
      for (int s = 0; s < 3; ++s) {
        int i = tid + 640 * s;
        if (i < 1520) {
          int r = i / 19, q = i - r * 19;
          *(f16x8*)(xa + r * 264 + 8 * q) = ph[s];
        }
      }
#pragma unroll
      for (int s = 0; s < 4; ++s) {
        int i = tid + 640 * s;
        if (i < 2000) {
          int r = i / 25, k2 = i - r * 25;
          xa[r * 264 + 152 + 2 * k2] = (f16)pt[s].x;
          xa[r * 264 + 153 + 2 * k2] = (f16)pt[s].y;
        }
      }
    }

#pragma unroll
    for (int m = 0; m < 5; ++m) {
#pragma unroll
      for (int q = 0; q < 4; ++q) {
        int row = 16 * m + qrow + q;
        float rg = sigmoid_f(aR[m][q] + bCr);
        float zg = sigmoid_f(aZ[m][q] + bCz);
        float ng = tanh_f(aNi[m][q] + bCi + rg * (aNh[m][q] + bCh));
        float h  = (1.0f - zg) * ng + zg * hp[m][q];
        hp[m][q] = h;
        if (jok) hls[row * 168 + j] = (f16)h;
      }
    }
    __syncthreads();
    f16* tsw = xc; xc = xa; xa = tsw;
  }

  f32x4 aR[5], aZ[5], aNh[5];
#pragma unroll
  for (int m = 0; m < 5; ++m) { aR[m] = 0.f; aZ[m] = 0.f; aNh[m] = 0.f; }
  for (int kt = 0; kt < KT_N; ++kt) {
    f16x8 br = WN[(kt * NTILE + w) * 64 + lane];
    f16x8 bz = WN[(kt * NTILE + 10 + w) * 64 + lane];
    f16x8 bn = WN[(kt * NTILE + 20 + w) * 64 + lane];
    const f16* ab = hls + kt * 32 + acol8;
#pragma unroll
    for (int m = 0; m < 5; ++m) {
      f16x8 a = *(const f16x8*)(ab + (16 * m + arow) * 168);
      aR[m]  = __builtin_amdgcn_mfma_f32_16x16x32_f16(a, br, aR[m], 0, 0, 0);
      aZ[m]  = __builtin_amdgcn_mfma_f32_16x16x32_f16(a, bz, aZ[m], 0, 0, 0);
      aNh[m] = __builtin_amdgcn_mfma_f32_16x16x32_f16(a, bn, aNh[m], 0, 0, 0);
    }
  }
#pragma unroll
  for (int m = 0; m < 5; ++m) {
#pragma unroll
    for (int q = 0; q < 4; ++q) {
      int row = 16 * m + qrow + q;
      float rg = sigmoid_f(aR[m][q] + bNr);
      float zg = sigmoid_f(aZ[m][q] + bNz);
      float ng = tanh_f(bNi + rg * (aNh[m][q] + bNh));
      float o  = (1.0f - zg) * ng + zg * hp[m][q];
      if (jok) out[(size_t)(t0 + row) * MEMD + j] = o;
    }
  }
}

}  // namespace r2

}  // namespace

extern "C" void kernel_launch(void* const* d_in, const int* in_sizes, int n_in,
                              void* d_out, int out_size, void* d_ws, size_t ws_size,
                              hipStream_t stream) {
  const float* embs       = (const float*)d_in[0];
  const float* tags       = (const float*)d_in[1];
  const float* tag_parent = (const float*)d_in[2];
  const float* w_ih_leaf  = (const float*)d_in[3];
  // d_in[4] w_hh_leaf unused (h0 = 0)
  const float* b_ih_leaf  = (const float*)d_in[5];
  const float* b_hh_leaf  = (const float*)d_in[6];
  const float* w_ih_child = (const float*)d_in[7];
  const float* w_hh_child = (const float*)d_in[8];
  const float* b_ih_child = (const float*)d_in[9];
  const float* b_hh_child = (const float*)d_in[10];
  // d_in[11] w_ih_node unused (x = 0)
  const float* w_hh_node  = (const float*)d_in[12];
  const float* b_ih_node  = (const float*)d_in[13];
  const float* b_hh_node  = (const float*)d_in[14];
  float* out = (float*)d_out;
  char*  ws  = (char*)d_ws;

  prep_kernel<<<228, 256, 0, stream>>>(w_ih_leaf, b_ih_leaf, b_hh_leaf,
                                       w_ih_child, w_hh_child, b_ih_child, b_hh_child,
                                       w_hh_node, b_ih_node, b_hh_node, ws);

  if (ws_size >= WS_R3) {
    constexpr int LEAF_LDS = (80 * 360 + 80 * 264) * 2;  // 99840
    hipFuncSetAttribute((const void*)leaf3_kernel,
                        hipFuncAttributeMaxDynamicSharedMemorySize, LEAF_LDS);
    leaf3_kernel<<<dim3(NBLK, CCH), 640, LEAF_LDS, stream>>>(embs, tags, tag_parent, ws);
    fold3_kernel<<<NBLK, 640, 0, stream>>>(ws, out);
  } else {
    r2::leaf_kernel<<<dim3(NBLK, CCH), 640, 0, stream>>>(embs, tags, ws);
    constexpr int FOLD_LDS = (2 * 80 * 264 + 80 * 168) * 2;  // 111360
    hipFuncSetAttribute((const void*)r2::fold_kernel,
                        hipFuncAttributeMaxDynamicSharedMemorySize, FOLD_LDS);
    r2::fold_kernel<<<NBLK, 640, FOLD_LDS, stream>>>(tags, tag_parent, ws, out);
  }
}